// Round 1
// baseline (1014.247 us; speedup 1.0000x reference)
//
#include <hip/hip_runtime.h>
#include <hip/hip_bf16.h>
#include <math.h>

// Problem dims (fixed)
#define C_IN 256
#define HW 128          // H = W = 128
#define NPIX (HW*HW)    // 16384
#define DIM_LOI 128
#define N_LINES 16000
#define N_PTS0 32
#define N_PTS1 8
#define DIM_FC 1024
#define N_LABELS 3

// ---------------------------------------------------------------------------
// Kernel 1: conv1x1  loi_hwc[p][o] = relu(sum_c w_fc1[o][c]*features[c][p] + b_fc1[o])
// GEMM M=NPIX(p) x N=128(o), K=256. Tile 128x128, BK=8, 8x8 per thread.
// Output channel-last so the pool kernel's gathers are coalesced over channels.
// ---------------------------------------------------------------------------
__global__ __launch_bounds__(256) void conv_gemm(
    const float* __restrict__ feats,   // (C_IN, NPIX)
    const float* __restrict__ w_fc1,   // (DIM_LOI, C_IN)
    const float* __restrict__ b_fc1,   // (DIM_LOI)
    float* __restrict__ loi)           // (NPIX, DIM_LOI) channel-last
{
    __shared__ float As[8][128];  // As[k][p]
    __shared__ float Bs[8][128];  // Bs[k][o]
    const int tid = threadIdx.x;
    const int tx = tid & 15, ty = tid >> 4;
    const int p0 = blockIdx.x * 128;

    float acc[8][8] = {};

    const int akr = tid >> 5;          // 0..7  k row for A
    const int ac4 = (tid & 31) * 4;    // pixel within tile (float4)
    const int bo  = tid >> 1;          // 0..127 output channel for B
    const int bk4 = (tid & 1) * 4;     // k within tile (float4)

    for (int k0 = 0; k0 < C_IN; k0 += 8) {
        float4 av = *(const float4*)(feats + (size_t)(k0 + akr) * NPIX + p0 + ac4);
        float4 bv = *(const float4*)(w_fc1 + (size_t)bo * C_IN + k0 + bk4);
        *(float4*)&As[akr][ac4] = av;
        Bs[bk4 + 0][bo] = bv.x;
        Bs[bk4 + 1][bo] = bv.y;
        Bs[bk4 + 2][bo] = bv.z;
        Bs[bk4 + 3][bo] = bv.w;
        __syncthreads();
#pragma unroll
        for (int kk = 0; kk < 8; ++kk) {
            float a[8], b[8];
#pragma unroll
            for (int i = 0; i < 8; ++i) a[i] = As[kk][ty * 8 + i];
#pragma unroll
            for (int j = 0; j < 8; ++j) b[j] = Bs[kk][tx * 8 + j];
#pragma unroll
            for (int i = 0; i < 8; ++i)
#pragma unroll
                for (int j = 0; j < 8; ++j) acc[i][j] += a[i] * b[j];
        }
        __syncthreads();
    }
#pragma unroll
    for (int i = 0; i < 8; ++i) {
        int p = p0 + ty * 8 + i;
#pragma unroll
        for (int j = 0; j < 8; ++j) {
            int o = tx * 8 + j;
            float v = acc[i][j] + b_fc1[o];
            loi[(size_t)p * DIM_LOI + o] = v > 0.0f ? v : 0.0f;
        }
    }
}

// ---------------------------------------------------------------------------
// Kernel 2: line pool. One block (128 threads) per line; thread = channel.
// feat[l][c*8+p] = max over 4 consecutive of 32 bilinear samples.
// ---------------------------------------------------------------------------
__global__ __launch_bounds__(128) void pool_kernel(
    const float* __restrict__ loi,     // (NPIX, DIM_LOI) channel-last
    const float* __restrict__ lines,   // (N_LINES, 4)
    float* __restrict__ feat)          // (N_LINES, 1024) = [l][c*8+p]
{
    __shared__ int   offs[N_PTS0][4];
    __shared__ float wts[N_PTS0][4];
    const int l = blockIdx.x;
    const int c = threadIdx.x;

    if (threadIdx.x < N_PTS0) {
        int j = threadIdx.x;
        float t = (float)j * (1.0f / 31.0f);
        float U0 = lines[4 * l + 0], U1 = lines[4 * l + 1];
        float V0 = lines[4 * l + 2], V1 = lines[4 * l + 3];
        float px = U0 * t + V0 * (1.0f - t) - 0.5f;
        float py = U1 * t + V1 * (1.0f - t) - 0.5f;
        float px0 = fminf(fmaxf(floorf(px), 0.0f), 127.0f);
        float py0 = fminf(fmaxf(floorf(py), 0.0f), 127.0f);
        float px1 = fminf(fmaxf(px0 + 1.0f, 0.0f), 127.0f);
        float py1 = fminf(fmaxf(py0 + 1.0f, 0.0f), 127.0f);
        int ix0 = (int)px0, iy0 = (int)py0, ix1 = (int)px1, iy1 = (int)py1;
        float wx0 = px1 - px, wx1 = px - px0;
        float wy0 = py1 - py, wy1 = py - py0;
        offs[j][0] = (iy0 * HW + ix0) * DIM_LOI;
        offs[j][1] = (iy1 * HW + ix0) * DIM_LOI;
        offs[j][2] = (iy0 * HW + ix1) * DIM_LOI;
        offs[j][3] = (iy1 * HW + ix1) * DIM_LOI;
        wts[j][0] = wy0 * wx0;
        wts[j][1] = wy1 * wx0;
        wts[j][2] = wy0 * wx1;
        wts[j][3] = wy1 * wx1;
    }
    __syncthreads();

#pragma unroll
    for (int p = 0; p < N_PTS1; ++p) {
        float best = -INFINITY;
#pragma unroll
        for (int q = 0; q < 4; ++q) {
            int j = p * 4 + q;
            float v = wts[j][0] * loi[offs[j][0] + c]
                    + wts[j][1] * loi[offs[j][1] + c]
                    + wts[j][2] * loi[offs[j][2] + c]
                    + wts[j][3] * loi[offs[j][3] + c];
            best = fmaxf(best, v);
        }
        feat[(size_t)l * (N_PTS1 * DIM_LOI) + c * N_PTS1 + p] = best;
    }
}

// ---------------------------------------------------------------------------
// Kernel 3/4: MLP GEMM  out[m][n] = act(sum_k A[m][k]*W[n][k] + bias[n])
// M=16000, N=1024, K=1024. Tile 128x128, BK=8, 8x8 per thread.
// ---------------------------------------------------------------------------
template <int RELU>
__global__ __launch_bounds__(256) void mlp_gemm(
    const float* __restrict__ A,      // (M, K) row-major
    const float* __restrict__ W,      // (N, K) row-major
    const float* __restrict__ bias,   // (N)
    float* __restrict__ out,          // (M, N)
    int M, int N, int K)
{
    __shared__ float As[8][128];  // As[k][m]
    __shared__ float Bs[8][128];  // Bs[k][n]
    const int tid = threadIdx.x;
    const int tx = tid & 15, ty = tid >> 4;
    const int m0 = blockIdx.x * 128;
    const int n0 = blockIdx.y * 128;

    float acc[8][8] = {};

    const int lrow = tid >> 1;         // 0..127
    const int lk4  = (tid & 1) * 4;    // k offset (float4)

    for (int k0 = 0; k0 < K; k0 += 8) {
        float4 av = *(const float4*)(A + (size_t)(m0 + lrow) * K + k0 + lk4);
        float4 bv = *(const float4*)(W + (size_t)(n0 + lrow) * K + k0 + lk4);
        As[lk4 + 0][lrow] = av.x;
        As[lk4 + 1][lrow] = av.y;
        As[lk4 + 2][lrow] = av.z;
        As[lk4 + 3][lrow] = av.w;
        Bs[lk4 + 0][lrow] = bv.x;
        Bs[lk4 + 1][lrow] = bv.y;
        Bs[lk4 + 2][lrow] = bv.z;
        Bs[lk4 + 3][lrow] = bv.w;
        __syncthreads();
#pragma unroll
        for (int kk = 0; kk < 8; ++kk) {
            float a[8], b[8];
#pragma unroll
            for (int i = 0; i < 8; ++i) a[i] = As[kk][ty * 8 + i];
#pragma unroll
            for (int j = 0; j < 8; ++j) b[j] = Bs[kk][tx * 8 + j];
#pragma unroll
            for (int i = 0; i < 8; ++i)
#pragma unroll
                for (int j = 0; j < 8; ++j) acc[i][j] += a[i] * b[j];
        }
        __syncthreads();
    }
#pragma unroll
    for (int i = 0; i < 8; ++i) {
        int m = m0 + ty * 8 + i;
#pragma unroll
        for (int j = 0; j < 8; ++j) {
            int n = n0 + tx * 8 + j;
            float v = acc[i][j] + bias[n];
            if (RELU) v = v > 0.0f ? v : 0.0f;
            out[(size_t)m * N + n] = v;
        }
    }
}

// ---------------------------------------------------------------------------
// Kernel 5: head. One wave per line: logits[l][n] = sum_k x2[l][k]*w3[n][k]+b3[n]
// ---------------------------------------------------------------------------
__global__ __launch_bounds__(256) void head_kernel(
    const float* __restrict__ x2,    // (N_LINES, 1024)
    const float* __restrict__ w3,    // (3, 1024)
    const float* __restrict__ b3,    // (3)
    float* __restrict__ out)         // (N_LINES, 3)
{
    const int gtid = blockIdx.x * blockDim.x + threadIdx.x;
    const int l = gtid >> 6;
    const int lane = threadIdx.x & 63;
    if (l >= N_LINES) return;
    const float* xr = x2 + (size_t)l * DIM_FC;
    float s0 = 0.0f, s1 = 0.0f, s2 = 0.0f;
#pragma unroll
    for (int it = 0; it < 4; ++it) {
        int k = it * 256 + lane * 4;
        float4 xv = *(const float4*)(xr + k);
        float4 wa = *(const float4*)(w3 + 0 * DIM_FC + k);
        float4 wb = *(const float4*)(w3 + 1 * DIM_FC + k);
        float4 wc = *(const float4*)(w3 + 2 * DIM_FC + k);
        s0 += xv.x * wa.x + xv.y * wa.y + xv.z * wa.z + xv.w * wa.w;
        s1 += xv.x * wb.x + xv.y * wb.y + xv.z * wb.z + xv.w * wb.w;
        s2 += xv.x * wc.x + xv.y * wc.y + xv.z * wc.z + xv.w * wc.w;
    }
#pragma unroll
    for (int off = 32; off > 0; off >>= 1) {
        s0 += __shfl_xor(s0, off);
        s1 += __shfl_xor(s1, off);
        s2 += __shfl_xor(s2, off);
    }
    if (lane == 0) {
        out[(size_t)l * 3 + 0] = s0 + b3[0];
        out[(size_t)l * 3 + 1] = s1 + b3[1];
        out[(size_t)l * 3 + 2] = s2 + b3[2];
    }
}

// ---------------------------------------------------------------------------
extern "C" void kernel_launch(void* const* d_in, const int* in_sizes, int n_in,
                              void* d_out, int out_size, void* d_ws, size_t ws_size,
                              hipStream_t stream) {
    const float* features = (const float*)d_in[0];  // (1,256,128,128)
    const float* lines    = (const float*)d_in[1];  // (16000,4)
    const float* w_fc1    = (const float*)d_in[2];  // (128,256)
    const float* b_fc1    = (const float*)d_in[3];  // (128)
    const float* w1       = (const float*)d_in[4];  // (1024,1024)
    const float* b1       = (const float*)d_in[5];  // (1024)
    const float* w2       = (const float*)d_in[6];  // (1024,1024)
    const float* b2       = (const float*)d_in[7];  // (1024)
    const float* w3       = (const float*)d_in[8];  // (3,1024)
    const float* b3       = (const float*)d_in[9];  // (3)
    float* out = (float*)d_out;

    // workspace layout (floats)
    float* ws = (float*)d_ws;
    float* loi  = ws;                                    // 16384*128   = 2,097,152
    float* feat = loi + (size_t)NPIX * DIM_LOI;          // 16000*1024  = 16,384,000
    float* x1   = feat + (size_t)N_LINES * DIM_FC;       // 16000*1024
    float* x2   = feat;                                  // reuse feat buffer

    // 1) conv1x1 -> channel-last loi
    conv_gemm<<<dim3(NPIX / 128), 256, 0, stream>>>(features, w_fc1, b_fc1, loi);

    // 2) line pooling -> feat (16000,1024)
    pool_kernel<<<dim3(N_LINES), 128, 0, stream>>>(loi, lines, feat);

    // 3) x1 = relu(feat @ w1^T + b1)
    mlp_gemm<1><<<dim3(N_LINES / 128, DIM_FC / 128), 256, 0, stream>>>(
        feat, w1, b1, x1, N_LINES, DIM_FC, DIM_FC);

    // 4) x2 = relu(x1 @ w2^T + b2)
    mlp_gemm<1><<<dim3(N_LINES / 128, DIM_FC / 128), 256, 0, stream>>>(
        x1, w2, b2, x2, N_LINES, DIM_FC, DIM_FC);

    // 5) logits = x2 @ w3^T + b3
    head_kernel<<<dim3((N_LINES * 64 + 255) / 256), 256, 0, stream>>>(x2, w3, b3, out);
}

// Round 2
// 383.150 us; speedup vs baseline: 2.6471x; 2.6471x over previous
//
#include <hip/hip_runtime.h>
#include <hip/hip_bf16.h>
#include <math.h>

// Problem dims (fixed)
#define C_IN 256
#define HW 128          // H = W = 128
#define NPIX (HW*HW)    // 16384
#define DIM_LOI 128
#define N_LINES 16000
#define N_PTS0 32
#define N_PTS1 8
#define DIM_FC 1024
#define N_LABELS 3

typedef __attribute__((ext_vector_type(8))) short short8;   // 8 bf16 = 4 VGPRs
typedef __attribute__((ext_vector_type(4))) float f32x4;

// ---------------------------------------------------------------------------
// Kernel 1: conv1x1  loi[p][o] = relu(sum_c w_fc1[o][c]*features[c][p] + b_fc1[o])
// fp32 GEMM M=16384 x N=128, K=256 (only ~1 GFLOP; keep fp32 vector).
// ---------------------------------------------------------------------------
__global__ __launch_bounds__(256) void conv_gemm(
    const float* __restrict__ feats,   // (C_IN, NPIX)
    const float* __restrict__ w_fc1,   // (DIM_LOI, C_IN)
    const float* __restrict__ b_fc1,   // (DIM_LOI)
    float* __restrict__ loi)           // (NPIX, DIM_LOI) channel-last
{
    __shared__ float As[8][128];  // As[k][p]
    __shared__ float Bs[8][128];  // Bs[k][o]
    const int tid = threadIdx.x;
    const int tx = tid & 15, ty = tid >> 4;
    const int p0 = blockIdx.x * 128;

    float acc[8][8] = {};

    const int akr = tid >> 5;          // 0..7  k row for A
    const int ac4 = (tid & 31) * 4;    // pixel within tile (float4)
    const int bo  = tid >> 1;          // 0..127 output channel for B
    const int bk4 = (tid & 1) * 4;     // k within tile (float4)

    for (int k0 = 0; k0 < C_IN; k0 += 8) {
        float4 av = *(const float4*)(feats + (size_t)(k0 + akr) * NPIX + p0 + ac4);
        float4 bv = *(const float4*)(w_fc1 + (size_t)bo * C_IN + k0 + bk4);
        *(float4*)&As[akr][ac4] = av;
        Bs[bk4 + 0][bo] = bv.x;
        Bs[bk4 + 1][bo] = bv.y;
        Bs[bk4 + 2][bo] = bv.z;
        Bs[bk4 + 3][bo] = bv.w;
        __syncthreads();
#pragma unroll
        for (int kk = 0; kk < 8; ++kk) {
            float a[8], b[8];
#pragma unroll
            for (int i = 0; i < 8; ++i) a[i] = As[kk][ty * 8 + i];
#pragma unroll
            for (int j = 0; j < 8; ++j) b[j] = Bs[kk][tx * 8 + j];
#pragma unroll
            for (int i = 0; i < 8; ++i)
#pragma unroll
                for (int j = 0; j < 8; ++j) acc[i][j] += a[i] * b[j];
        }
        __syncthreads();
    }
#pragma unroll
    for (int i = 0; i < 8; ++i) {
        int p = p0 + ty * 8 + i;
#pragma unroll
        for (int j = 0; j < 8; ++j) {
            int o = tx * 8 + j;
            float v = acc[i][j] + b_fc1[o];
            loi[(size_t)p * DIM_LOI + o] = v > 0.0f ? v : 0.0f;
        }
    }
}

// ---------------------------------------------------------------------------
// Kernel 2: line pool (fp32 math, bf16 output). One block (128 thr) per line.
// feat[l][c*8+p] = max over 4 consecutive of 32 bilinear samples.
// ---------------------------------------------------------------------------
__global__ __launch_bounds__(128) void pool_kernel(
    const float* __restrict__ loi,           // (NPIX, DIM_LOI) channel-last
    const float* __restrict__ lines,         // (N_LINES, 4)
    __hip_bfloat16* __restrict__ feat)       // (N_LINES, 1024) = [l][c*8+p]
{
    __shared__ int   offs[N_PTS0][4];
    __shared__ float wts[N_PTS0][4];
    const int l = blockIdx.x;
    const int c = threadIdx.x;

    if (threadIdx.x < N_PTS0) {
        int j = threadIdx.x;
        float t = (float)j * (1.0f / 31.0f);
        float U0 = lines[4 * l + 0], U1 = lines[4 * l + 1];
        float V0 = lines[4 * l + 2], V1 = lines[4 * l + 3];
        float px = U0 * t + V0 * (1.0f - t) - 0.5f;
        float py = U1 * t + V1 * (1.0f - t) - 0.5f;
        float px0 = fminf(fmaxf(floorf(px), 0.0f), 127.0f);
        float py0 = fminf(fmaxf(floorf(py), 0.0f), 127.0f);
        float px1 = fminf(fmaxf(px0 + 1.0f, 0.0f), 127.0f);
        float py1 = fminf(fmaxf(py0 + 1.0f, 0.0f), 127.0f);
        int ix0 = (int)px0, iy0 = (int)py0, ix1 = (int)px1, iy1 = (int)py1;
        float wx0 = px1 - px, wx1 = px - px0;
        float wy0 = py1 - py, wy1 = py - py0;
        offs[j][0] = (iy0 * HW + ix0) * DIM_LOI;
        offs[j][1] = (iy1 * HW + ix0) * DIM_LOI;
        offs[j][2] = (iy0 * HW + ix1) * DIM_LOI;
        offs[j][3] = (iy1 * HW + ix1) * DIM_LOI;
        wts[j][0] = wy0 * wx0;
        wts[j][1] = wy1 * wx0;
        wts[j][2] = wy0 * wx1;
        wts[j][3] = wy1 * wx1;
    }
    __syncthreads();

#pragma unroll
    for (int p = 0; p < N_PTS1; ++p) {
        float best = -INFINITY;
#pragma unroll
        for (int q = 0; q < 4; ++q) {
            int j = p * 4 + q;
            float v = wts[j][0] * loi[offs[j][0] + c]
                    + wts[j][1] * loi[offs[j][1] + c]
                    + wts[j][2] * loi[offs[j][2] + c]
                    + wts[j][3] * loi[offs[j][3] + c];
            best = fmaxf(best, v);
        }
        feat[(size_t)l * (N_PTS1 * DIM_LOI) + c * N_PTS1 + p] = __float2bfloat16(best);
    }
}

// ---------------------------------------------------------------------------
// fp32 -> bf16 conversion (for weights)
// ---------------------------------------------------------------------------
__global__ __launch_bounds__(256) void to_bf16(
    const float* __restrict__ src, __hip_bfloat16* __restrict__ dst, int n4)
{
    int i = blockIdx.x * blockDim.x + threadIdx.x;
    if (i < n4) {
        float4 v = *(const float4*)(src + (size_t)i * 4);
        dst[(size_t)i * 4 + 0] = __float2bfloat16(v.x);
        dst[(size_t)i * 4 + 1] = __float2bfloat16(v.y);
        dst[(size_t)i * 4 + 2] = __float2bfloat16(v.z);
        dst[(size_t)i * 4 + 3] = __float2bfloat16(v.w);
    }
}

// ---------------------------------------------------------------------------
// MFMA bf16 GEMM: out[m][n] = act(sum_k A[m][k]*B[n][k] + bias[n])
// 128x128 tile, BK=32, 4 waves in 2x2, each wave 4x4 of 16x16x32 MFMA.
// A,B staged via global_load_lds width=16; LDS tiles [128][32] bf16 unpadded.
// ---------------------------------------------------------------------------
template <int RELU, typename OutT>
__global__ __launch_bounds__(256) void mfma_gemm(
    const __hip_bfloat16* __restrict__ A,   // (M, K) row-major
    const __hip_bfloat16* __restrict__ B,   // (N, K) row-major (= B^T)
    const float* __restrict__ bias,         // (N)
    OutT* __restrict__ out,                 // (M, N)
    int M, int N, int K)
{
    __shared__ __hip_bfloat16 As[128 * 32];   // 8 KB
    __shared__ __hip_bfloat16 Bs[128 * 32];   // 8 KB
    const int tid  = threadIdx.x;
    const int lane = tid & 63;
    const int wave = tid >> 6;
    const int wr = wave >> 1, wc = wave & 1;    // 2x2 wave grid
    const int quad = lane >> 4;
    const int l16  = lane & 15;
    const int m0 = blockIdx.x * 128, n0 = blockIdx.y * 128;

    f32x4 acc[4][4];
#pragma unroll
    for (int i = 0; i < 4; ++i)
#pragma unroll
        for (int j = 0; j < 4; ++j) { f32x4 z = {0.f, 0.f, 0.f, 0.f}; acc[i][j] = z; }

    for (int k0 = 0; k0 < K; k0 += 32) {
        // ---- stage A,B tiles: 8 KB each; 2 sites x 256 thr x 16 B ----
#pragma unroll
        for (int s = 0; s < 2; ++s) {
            int li  = s * 256 + tid;         // 16B-chunk index 0..511
            int row = li >> 2;               // 0..127
            int ke  = (li & 3) * 8;          // element offset in k
            const __hip_bfloat16* ga = A + (size_t)(m0 + row) * K + k0 + ke;
            const __hip_bfloat16* gb = B + (size_t)(n0 + row) * K + k0 + ke;
            int chunk = s * 256 + (tid & ~63);  // wave-uniform base chunk
            __builtin_amdgcn_global_load_lds(
                (const __attribute__((address_space(1))) unsigned int*)ga,
                (__attribute__((address_space(3))) unsigned int*)(As + chunk * 8),
                16, 0, 0);
            __builtin_amdgcn_global_load_lds(
                (const __attribute__((address_space(1))) unsigned int*)gb,
                (__attribute__((address_space(3))) unsigned int*)(Bs + chunk * 8),
                16, 0, 0);
        }
        __syncthreads();

        // ---- fragments + MFMA ----
        short8 af[4], bf[4];
#pragma unroll
        for (int mt = 0; mt < 4; ++mt) {
            int row = wr * 64 + mt * 16 + l16;
            af[mt] = *(const short8*)((const short*)As + row * 32 + quad * 8);
        }
#pragma unroll
        for (int nt = 0; nt < 4; ++nt) {
            int row = wc * 64 + nt * 16 + l16;
            bf[nt] = *(const short8*)((const short*)Bs + row * 32 + quad * 8);
        }
#pragma unroll
        for (int mt = 0; mt < 4; ++mt)
#pragma unroll
            for (int nt = 0; nt < 4; ++nt)
                acc[mt][nt] = __builtin_amdgcn_mfma_f32_16x16x32_bf16(
                    af[mt], bf[nt], acc[mt][nt], 0, 0, 0);
        __syncthreads();
    }

    // ---- epilogue: C row = quad*4 + r, col = l16 ----
#pragma unroll
    for (int nt = 0; nt < 4; ++nt) {
        int n = n0 + wc * 64 + nt * 16 + l16;
        float bv = bias[n];
#pragma unroll
        for (int mt = 0; mt < 4; ++mt) {
            int mbase = m0 + wr * 64 + mt * 16 + quad * 4;
#pragma unroll
            for (int r = 0; r < 4; ++r) {
                float v = acc[mt][nt][r] + bv;
                if (RELU) v = v > 0.0f ? v : 0.0f;
                out[(size_t)(mbase + r) * N + n] = (OutT)v;
            }
        }
    }
}

// ---------------------------------------------------------------------------
// Head: one wave per line: logits[l][n] = sum_k x2[l][k]*w3[n][k] + b3[n]
// x2 is bf16, w3/b3 fp32.
// ---------------------------------------------------------------------------
__global__ __launch_bounds__(256) void head_kernel(
    const __hip_bfloat16* __restrict__ x2,  // (N_LINES, 1024) bf16
    const float* __restrict__ w3,           // (3, 1024)
    const float* __restrict__ b3,           // (3)
    float* __restrict__ out)                // (N_LINES, 3)
{
    const int gtid = blockIdx.x * blockDim.x + threadIdx.x;
    const int l = gtid >> 6;
    const int lane = threadIdx.x & 63;
    if (l >= N_LINES) return;
    const __hip_bfloat16* xr = x2 + (size_t)l * DIM_FC;
    float s0 = 0.0f, s1 = 0.0f, s2 = 0.0f;
#pragma unroll
    for (int it = 0; it < 4; ++it) {
        int k = it * 256 + lane * 4;
        ushort4 xv = *(const ushort4*)(xr + k);
        float x0 = __uint_as_float((unsigned)xv.x << 16);
        float x1 = __uint_as_float((unsigned)xv.y << 16);
        float x2v = __uint_as_float((unsigned)xv.z << 16);
        float x3 = __uint_as_float((unsigned)xv.w << 16);
        float4 wa = *(const float4*)(w3 + 0 * DIM_FC + k);
        float4 wb = *(const float4*)(w3 + 1 * DIM_FC + k);
        float4 wc = *(const float4*)(w3 + 2 * DIM_FC + k);
        s0 += x0 * wa.x + x1 * wa.y + x2v * wa.z + x3 * wa.w;
        s1 += x0 * wb.x + x1 * wb.y + x2v * wb.z + x3 * wb.w;
        s2 += x0 * wc.x + x1 * wc.y + x2v * wc.z + x3 * wc.w;
    }
#pragma unroll
    for (int off = 32; off > 0; off >>= 1) {
        s0 += __shfl_xor(s0, off);
        s1 += __shfl_xor(s1, off);
        s2 += __shfl_xor(s2, off);
    }
    if (lane == 0) {
        out[(size_t)l * 3 + 0] = s0 + b3[0];
        out[(size_t)l * 3 + 1] = s1 + b3[1];
        out[(size_t)l * 3 + 2] = s2 + b3[2];
    }
}

// ---------------------------------------------------------------------------
extern "C" void kernel_launch(void* const* d_in, const int* in_sizes, int n_in,
                              void* d_out, int out_size, void* d_ws, size_t ws_size,
                              hipStream_t stream) {
    const float* features = (const float*)d_in[0];  // (1,256,128,128)
    const float* lines    = (const float*)d_in[1];  // (16000,4)
    const float* w_fc1    = (const float*)d_in[2];  // (128,256)
    const float* b_fc1    = (const float*)d_in[3];  // (128)
    const float* w1       = (const float*)d_in[4];  // (1024,1024)
    const float* b1       = (const float*)d_in[5];  // (1024)
    const float* w2       = (const float*)d_in[6];  // (1024,1024)
    const float* b2       = (const float*)d_in[7];  // (1024)
    const float* w3       = (const float*)d_in[8];  // (3,1024)
    const float* b3       = (const float*)d_in[9];  // (3)
    float* out = (float*)d_out;

    // workspace layout (bytes):
    // loi  fp32  : 16384*128*4  =  8 MB
    // featb bf16 : 16000*1024*2 = 32 MB
    // x1b  bf16  : 32 MB
    // x2b  bf16  : 32 MB
    // w1b  bf16  :  2 MB
    // w2b  bf16  :  2 MB          total 108 MB
    char* ws = (char*)d_ws;
    float*          loi   = (float*)ws;
    __hip_bfloat16* featb = (__hip_bfloat16*)(ws + (size_t)8 * 1024 * 1024);
    __hip_bfloat16* x1b   = (__hip_bfloat16*)(ws + (size_t)40 * 1024 * 1024);
    __hip_bfloat16* x2b   = (__hip_bfloat16*)(ws + (size_t)72 * 1024 * 1024);
    __hip_bfloat16* w1b   = (__hip_bfloat16*)(ws + (size_t)104 * 1024 * 1024);
    __hip_bfloat16* w2b   = (__hip_bfloat16*)(ws + (size_t)106 * 1024 * 1024);

    // 0) weights -> bf16
    to_bf16<<<dim3((DIM_FC * DIM_FC / 4 + 255) / 256), 256, 0, stream>>>(w1, w1b, DIM_FC * DIM_FC / 4);
    to_bf16<<<dim3((DIM_FC * DIM_FC / 4 + 255) / 256), 256, 0, stream>>>(w2, w2b, DIM_FC * DIM_FC / 4);

    // 1) conv1x1 -> channel-last loi (fp32)
    conv_gemm<<<dim3(NPIX / 128), 256, 0, stream>>>(features, w_fc1, b_fc1, loi);

    // 2) line pooling -> featb (16000,1024) bf16
    pool_kernel<<<dim3(N_LINES), 128, 0, stream>>>(loi, lines, featb);

    // 3) x1 = relu(feat @ w1^T + b1)   bf16 out
    mfma_gemm<1, __hip_bfloat16><<<dim3(N_LINES / 128, DIM_FC / 128), 256, 0, stream>>>(
        featb, w1b, b1, x1b, N_LINES, DIM_FC, DIM_FC);

    // 4) x2 = relu(x1 @ w2^T + b2)    bf16 out
    mfma_gemm<1, __hip_bfloat16><<<dim3(N_LINES / 128, DIM_FC / 128), 256, 0, stream>>>(
        x1b, w2b, b2, x2b, N_LINES, DIM_FC, DIM_FC);

    // 5) logits = x2 @ w3^T + b3
    head_kernel<<<dim3((N_LINES * 64 + 255) / 256), 256, 0, stream>>>(x2b, w3, b3, out);
}

// Round 3
// 286.534 us; speedup vs baseline: 3.5397x; 1.3372x over previous
//
#include <hip/hip_runtime.h>
#include <hip/hip_bf16.h>
#include <math.h>

// Problem dims (fixed)
#define C_IN 256
#define HW 128          // H = W = 128
#define NPIX (HW*HW)    // 16384
#define DIM_LOI 128
#define N_LINES 16000
#define N_PTS0 32
#define N_PTS1 8
#define DIM_FC 1024
#define N_LABELS 3

typedef __attribute__((ext_vector_type(8))) short short8;   // 8 bf16 = 4 VGPRs
typedef __attribute__((ext_vector_type(4))) float f32x4;

// ---------------------------------------------------------------------------
// Kernel 1: conv1x1  loi[p][o] = relu(sum_c w_fc1[o][c]*features[c][p] + b_fc1[o])
// fp32 math, bf16 channel-last output (4 MB -> fits per-XCD L2 for the pool).
// ---------------------------------------------------------------------------
__global__ __launch_bounds__(256) void conv_gemm(
    const float* __restrict__ feats,   // (C_IN, NPIX)
    const float* __restrict__ w_fc1,   // (DIM_LOI, C_IN)
    const float* __restrict__ b_fc1,   // (DIM_LOI)
    __hip_bfloat16* __restrict__ loi)  // (NPIX, DIM_LOI) bf16 channel-last
{
    __shared__ float As[8][128];  // As[k][p]
    __shared__ float Bs[8][128];  // Bs[k][o]
    const int tid = threadIdx.x;
    const int tx = tid & 15, ty = tid >> 4;
    const int p0 = blockIdx.x * 128;

    float acc[8][8] = {};

    const int akr = tid >> 5;          // 0..7  k row for A
    const int ac4 = (tid & 31) * 4;    // pixel within tile (float4)
    const int bo  = tid >> 1;          // 0..127 output channel for B
    const int bk4 = (tid & 1) * 4;     // k within tile (float4)

    for (int k0 = 0; k0 < C_IN; k0 += 8) {
        float4 av = *(const float4*)(feats + (size_t)(k0 + akr) * NPIX + p0 + ac4);
        float4 bv = *(const float4*)(w_fc1 + (size_t)bo * C_IN + k0 + bk4);
        *(float4*)&As[akr][ac4] = av;
        Bs[bk4 + 0][bo] = bv.x;
        Bs[bk4 + 1][bo] = bv.y;
        Bs[bk4 + 2][bo] = bv.z;
        Bs[bk4 + 3][bo] = bv.w;
        __syncthreads();
#pragma unroll
        for (int kk = 0; kk < 8; ++kk) {
            float a[8], b[8];
#pragma unroll
            for (int i = 0; i < 8; ++i) a[i] = As[kk][ty * 8 + i];
#pragma unroll
            for (int j = 0; j < 8; ++j) b[j] = Bs[kk][tx * 8 + j];
#pragma unroll
            for (int i = 0; i < 8; ++i)
#pragma unroll
                for (int j = 0; j < 8; ++j) acc[i][j] += a[i] * b[j];
        }
        __syncthreads();
    }
#pragma unroll
    for (int i = 0; i < 8; ++i) {
        int p = p0 + ty * 8 + i;
        union { __hip_bfloat16 h[8]; uint4 u4; } pk;
#pragma unroll
        for (int j = 0; j < 8; ++j) {
            float v = acc[i][j] + b_fc1[tx * 8 + j];
            pk.h[j] = __float2bfloat16(v > 0.0f ? v : 0.0f);
        }
        *(uint4*)(loi + (size_t)p * DIM_LOI + tx * 8) = pk.u4;
    }
}

// ---------------------------------------------------------------------------
// Kernel 2: line pool. 256 thr = 4 lines x 64 lanes; lane owns 2 channels
// (uint gathers). feat layout k' = p*128 + c (coalesced uint stores);
// w1 is permuted to the same k order.
// ---------------------------------------------------------------------------
__global__ __launch_bounds__(256) void pool_kernel(
    const __hip_bfloat16* __restrict__ loi,   // (NPIX, 128) bf16 channel-last
    const float* __restrict__ lines,          // (N_LINES, 4)
    __hip_bfloat16* __restrict__ feat)        // (N_LINES, 1024), k' = p*128+c
{
    __shared__ int   offs[4][N_PTS0][4];      // uint-index base (elements/2)
    __shared__ float wts[4][N_PTS0][4];
    const int g = threadIdx.x >> 6;   // line group in block
    const int t = threadIdx.x & 63;   // lane; owns channels 2t, 2t+1
    const int l = blockIdx.x * 4 + g;

    if (t < N_PTS0) {
        int j = t;
        float tt = (float)j * (1.0f / 31.0f);
        float U0 = lines[4 * l + 0], U1 = lines[4 * l + 1];
        float V0 = lines[4 * l + 2], V1 = lines[4 * l + 3];
        float px = U0 * tt + V0 * (1.0f - tt) - 0.5f;
        float py = U1 * tt + V1 * (1.0f - tt) - 0.5f;
        float px0 = fminf(fmaxf(floorf(px), 0.0f), 127.0f);
        float py0 = fminf(fmaxf(floorf(py), 0.0f), 127.0f);
        float px1 = fminf(fmaxf(px0 + 1.0f, 0.0f), 127.0f);
        float py1 = fminf(fmaxf(py0 + 1.0f, 0.0f), 127.0f);
        int ix0 = (int)px0, iy0 = (int)py0, ix1 = (int)px1, iy1 = (int)py1;
        float wx0 = px1 - px, wx1 = px - px0;
        float wy0 = py1 - py, wy1 = py - py0;
        // uint-granular base offsets: (pix*128 + 2t)/2 = pix*64 + t
        offs[g][j][0] = (iy0 * HW + ix0) * 64;
        offs[g][j][1] = (iy1 * HW + ix0) * 64;
        offs[g][j][2] = (iy0 * HW + ix1) * 64;
        offs[g][j][3] = (iy1 * HW + ix1) * 64;
        wts[g][j][0] = wy0 * wx0;
        wts[g][j][1] = wy1 * wx0;
        wts[g][j][2] = wy0 * wx1;
        wts[g][j][3] = wy1 * wx1;
    }
    __syncthreads();

    const unsigned int* loi32 = (const unsigned int*)loi;
    unsigned int* featw = (unsigned int*)(feat + (size_t)l * (N_PTS1 * DIM_LOI));

#pragma unroll
    for (int p = 0; p < N_PTS1; ++p) {
        float b0 = -INFINITY, b1 = -INFINITY;
#pragma unroll
        for (int q = 0; q < 4; ++q) {
            int j = p * 4 + q;
            unsigned int v0 = loi32[offs[g][j][0] + t];
            unsigned int v1 = loi32[offs[g][j][1] + t];
            unsigned int v2 = loi32[offs[g][j][2] + t];
            unsigned int v3 = loi32[offs[g][j][3] + t];
            float w0 = wts[g][j][0], w1 = wts[g][j][1];
            float w2 = wts[g][j][2], w3 = wts[g][j][3];
            float sl = w0 * __uint_as_float(v0 << 16)
                     + w1 * __uint_as_float(v1 << 16)
                     + w2 * __uint_as_float(v2 << 16)
                     + w3 * __uint_as_float(v3 << 16);
            float sh = w0 * __uint_as_float(v0 & 0xffff0000u)
                     + w1 * __uint_as_float(v1 & 0xffff0000u)
                     + w2 * __uint_as_float(v2 & 0xffff0000u)
                     + w3 * __uint_as_float(v3 & 0xffff0000u);
            b0 = fmaxf(b0, sl);
            b1 = fmaxf(b1, sh);
        }
        union { __hip_bfloat16 h[2]; unsigned int u; } pk;
        pk.h[0] = __float2bfloat16(b0);
        pk.h[1] = __float2bfloat16(b1);
        featw[p * 64 + t] = pk.u;   // element p*128 + 2t
    }
}

// ---------------------------------------------------------------------------
// fp32 -> bf16 conversion (w2), and permuting conversion (w1: k = c*8+p -> p*128+c)
// ---------------------------------------------------------------------------
__global__ __launch_bounds__(256) void to_bf16(
    const float* __restrict__ src, __hip_bfloat16* __restrict__ dst, int n4)
{
    int i = blockIdx.x * blockDim.x + threadIdx.x;
    if (i < n4) {
        float4 v = *(const float4*)(src + (size_t)i * 4);
        dst[(size_t)i * 4 + 0] = __float2bfloat16(v.x);
        dst[(size_t)i * 4 + 1] = __float2bfloat16(v.y);
        dst[(size_t)i * 4 + 2] = __float2bfloat16(v.z);
        dst[(size_t)i * 4 + 3] = __float2bfloat16(v.w);
    }
}

__global__ __launch_bounds__(256) void permute_w1(
    const float* __restrict__ w1, __hip_bfloat16* __restrict__ w1p)
{
    int n = blockIdx.x;                     // 0..1023
    const float* src = w1 + (size_t)n * 1024;
    __hip_bfloat16* dst = w1p + (size_t)n * 1024;
    for (int k = threadIdx.x; k < 1024; k += 256) {
        int p = k >> 7, c = k & 127;        // k' = p*128 + c
        dst[k] = __float2bfloat16(src[c * 8 + p]);
    }
}

// ---------------------------------------------------------------------------
// MFMA bf16 GEMM: out[m][n] = act(sum_k A[m][k]*B[n][k] + bias[n])
// 128x128 tile, BK=32, 4 waves in 2x2, each wave 4x4 of 16x16x32 MFMA.
// ---------------------------------------------------------------------------
template <int RELU, typename OutT>
__global__ __launch_bounds__(256) void mfma_gemm(
    const __hip_bfloat16* __restrict__ A,   // (M, K) row-major
    const __hip_bfloat16* __restrict__ B,   // (N, K) row-major (= B^T)
    const float* __restrict__ bias,         // (N)
    OutT* __restrict__ out,                 // (M, N)
    int M, int N, int K)
{
    __shared__ __hip_bfloat16 As[128 * 32];   // 8 KB
    __shared__ __hip_bfloat16 Bs[128 * 32];   // 8 KB
    const int tid  = threadIdx.x;
    const int lane = tid & 63;
    const int wave = tid >> 6;
    const int wr = wave >> 1, wc = wave & 1;    // 2x2 wave grid
    const int quad = lane >> 4;
    const int l16  = lane & 15;
    const int m0 = blockIdx.x * 128, n0 = blockIdx.y * 128;

    f32x4 acc[4][4];
#pragma unroll
    for (int i = 0; i < 4; ++i)
#pragma unroll
        for (int j = 0; j < 4; ++j) { f32x4 z = {0.f, 0.f, 0.f, 0.f}; acc[i][j] = z; }

    for (int k0 = 0; k0 < K; k0 += 32) {
        // ---- stage A,B tiles: 8 KB each; 2 sites x 256 thr x 16 B ----
#pragma unroll
        for (int s = 0; s < 2; ++s) {
            int li  = s * 256 + tid;         // 16B-chunk index 0..511
            int row = li >> 2;               // 0..127
            int ke  = (li & 3) * 8;          // element offset in k
            const __hip_bfloat16* ga = A + (size_t)(m0 + row) * K + k0 + ke;
            const __hip_bfloat16* gb = B + (size_t)(n0 + row) * K + k0 + ke;
            int chunk = s * 256 + (tid & ~63);  // wave-uniform base chunk
            __builtin_amdgcn_global_load_lds(
                (const __attribute__((address_space(1))) unsigned int*)ga,
                (__attribute__((address_space(3))) unsigned int*)(As + chunk * 8),
                16, 0, 0);
            __builtin_amdgcn_global_load_lds(
                (const __attribute__((address_space(1))) unsigned int*)gb,
                (__attribute__((address_space(3))) unsigned int*)(Bs + chunk * 8),
                16, 0, 0);
        }
        __syncthreads();

        // ---- fragments + MFMA ----
        short8 af[4], bf[4];
#pragma unroll
        for (int mt = 0; mt < 4; ++mt) {
            int row = wr * 64 + mt * 16 + l16;
            af[mt] = *(const short8*)((const short*)As + row * 32 + quad * 8);
        }
#pragma unroll
        for (int nt = 0; nt < 4; ++nt) {
            int row = wc * 64 + nt * 16 + l16;
            bf[nt] = *(const short8*)((const short*)Bs + row * 32 + quad * 8);
        }
#pragma unroll
        for (int mt = 0; mt < 4; ++mt)
#pragma unroll
            for (int nt = 0; nt < 4; ++nt)
                acc[mt][nt] = __builtin_amdgcn_mfma_f32_16x16x32_bf16(
                    af[mt], bf[nt], acc[mt][nt], 0, 0, 0);
        __syncthreads();
    }

    // ---- epilogue: C row = quad*4 + r, col = l16 ----
#pragma unroll
    for (int nt = 0; nt < 4; ++nt) {
        int n = n0 + wc * 64 + nt * 16 + l16;
        float bv = bias[n];
#pragma unroll
        for (int mt = 0; mt < 4; ++mt) {
            int mbase = m0 + wr * 64 + mt * 16 + quad * 4;
#pragma unroll
            for (int r = 0; r < 4; ++r) {
                float v = acc[mt][nt][r] + bv;
                if (RELU) v = v > 0.0f ? v : 0.0f;
                out[(size_t)(mbase + r) * N + n] = (OutT)v;
            }
        }
    }
}

// ---------------------------------------------------------------------------
// Head: one wave per line: logits[l][n] = sum_k x2[l][k]*w3[n][k] + b3[n]
// ---------------------------------------------------------------------------
__global__ __launch_bounds__(256) void head_kernel(
    const __hip_bfloat16* __restrict__ x2,  // (N_LINES, 1024) bf16
    const float* __restrict__ w3,           // (3, 1024)
    const float* __restrict__ b3,           // (3)
    float* __restrict__ out)                // (N_LINES, 3)
{
    const int gtid = blockIdx.x * blockDim.x + threadIdx.x;
    const int l = gtid >> 6;
    const int lane = threadIdx.x & 63;
    if (l >= N_LINES) return;
    const __hip_bfloat16* xr = x2 + (size_t)l * DIM_FC;
    float s0 = 0.0f, s1 = 0.0f, s2 = 0.0f;
#pragma unroll
    for (int it = 0; it < 4; ++it) {
        int k = it * 256 + lane * 4;
        ushort4 xv = *(const ushort4*)(xr + k);
        float x0 = __uint_as_float((unsigned)xv.x << 16);
        float x1 = __uint_as_float((unsigned)xv.y << 16);
        float x2v = __uint_as_float((unsigned)xv.z << 16);
        float x3 = __uint_as_float((unsigned)xv.w << 16);
        float4 wa = *(const float4*)(w3 + 0 * DIM_FC + k);
        float4 wb = *(const float4*)(w3 + 1 * DIM_FC + k);
        float4 wc = *(const float4*)(w3 + 2 * DIM_FC + k);
        s0 += x0 * wa.x + x1 * wa.y + x2v * wa.z + x3 * wa.w;
        s1 += x0 * wb.x + x1 * wb.y + x2v * wb.z + x3 * wb.w;
        s2 += x0 * wc.x + x1 * wc.y + x2v * wc.z + x3 * wc.w;
    }
#pragma unroll
    for (int off = 32; off > 0; off >>= 1) {
        s0 += __shfl_xor(s0, off);
        s1 += __shfl_xor(s1, off);
        s2 += __shfl_xor(s2, off);
    }
    if (lane == 0) {
        out[(size_t)l * 3 + 0] = s0 + b3[0];
        out[(size_t)l * 3 + 1] = s1 + b3[1];
        out[(size_t)l * 3 + 2] = s2 + b3[2];
    }
}

// ---------------------------------------------------------------------------
extern "C" void kernel_launch(void* const* d_in, const int* in_sizes, int n_in,
                              void* d_out, int out_size, void* d_ws, size_t ws_size,
                              hipStream_t stream) {
    const float* features = (const float*)d_in[0];  // (1,256,128,128)
    const float* lines    = (const float*)d_in[1];  // (16000,4)
    const float* w_fc1    = (const float*)d_in[2];  // (128,256)
    const float* b_fc1    = (const float*)d_in[3];  // (128)
    const float* w1       = (const float*)d_in[4];  // (1024,1024)
    const float* b1       = (const float*)d_in[5];  // (1024)
    const float* w2       = (const float*)d_in[6];  // (1024,1024)
    const float* b2       = (const float*)d_in[7];  // (1024)
    const float* w3       = (const float*)d_in[8];  // (3,1024)
    const float* b3       = (const float*)d_in[9];  // (3)
    float* out = (float*)d_out;

    // workspace layout (bytes):
    // loi   bf16 : 16384*128*2  =  4 MB   @ 0
    // featb bf16 : 16000*1024*2 = 32 MB   @ 8 MB
    // x1b   bf16 : 32 MB                  @ 40 MB
    // x2b   bf16 : 32 MB                  @ 72 MB
    // w1b   bf16 :  2 MB                  @ 104 MB
    // w2b   bf16 :  2 MB                  @ 106 MB
    char* ws = (char*)d_ws;
    __hip_bfloat16* loi   = (__hip_bfloat16*)ws;
    __hip_bfloat16* featb = (__hip_bfloat16*)(ws + (size_t)8 * 1024 * 1024);
    __hip_bfloat16* x1b   = (__hip_bfloat16*)(ws + (size_t)40 * 1024 * 1024);
    __hip_bfloat16* x2b   = (__hip_bfloat16*)(ws + (size_t)72 * 1024 * 1024);
    __hip_bfloat16* w1b   = (__hip_bfloat16*)(ws + (size_t)104 * 1024 * 1024);
    __hip_bfloat16* w2b   = (__hip_bfloat16*)(ws + (size_t)106 * 1024 * 1024);

    // 0) weights -> bf16 (w1 permuted to k' = p*128+c to match feat layout)
    permute_w1<<<dim3(DIM_FC), 256, 0, stream>>>(w1, w1b);
    to_bf16<<<dim3((DIM_FC * DIM_FC / 4 + 255) / 256), 256, 0, stream>>>(w2, w2b, DIM_FC * DIM_FC / 4);

    // 1) conv1x1 -> channel-last bf16 loi
    conv_gemm<<<dim3(NPIX / 128), 256, 0, stream>>>(features, w_fc1, b_fc1, loi);

    // 2) line pooling -> featb (16000,1024) bf16, k' = p*128+c
    pool_kernel<<<dim3(N_LINES / 4), 256, 0, stream>>>(loi, lines, featb);

    // 3) x1 = relu(feat @ w1p^T + b1)
    mfma_gemm<1, __hip_bfloat16><<<dim3(N_LINES / 128, DIM_FC / 128), 256, 0, stream>>>(
        featb, w1b, b1, x1b, N_LINES, DIM_FC, DIM_FC);

    // 4) x2 = relu(x1 @ w2^T + b2)
    mfma_gemm<1, __hip_bfloat16><<<dim3(N_LINES / 128, DIM_FC / 128), 256, 0, stream>>>(
        x1b, w2b, b2, x2b, N_LINES, DIM_FC, DIM_FC);

    // 5) logits = x2 @ w3^T + b3
    head_kernel<<<dim3((N_LINES * 64 + 255) / 256), 256, 0, stream>>>(x2b, w3, b3, out);
}

// Round 4
// 255.055 us; speedup vs baseline: 3.9766x; 1.1234x over previous
//
#include <hip/hip_runtime.h>
#include <hip/hip_bf16.h>
#include <math.h>

// Problem dims (fixed)
#define C_IN 256
#define HW 128          // H = W = 128
#define NPIX (HW*HW)    // 16384
#define DIM_LOI 128
#define N_LINES 16000
#define N_PTS0 32
#define N_PTS1 8
#define DIM_FC 1024
#define N_LABELS 3

typedef __attribute__((ext_vector_type(8))) short short8;   // 8 bf16 = 4 VGPRs
typedef __attribute__((ext_vector_type(4))) float f32x4;

// ---------------------------------------------------------------------------
// Transpose + bf16: features (256, 16384) fp32 -> featsT (16384, 256) bf16
// ---------------------------------------------------------------------------
__global__ __launch_bounds__(256) void transpose_feats(
    const float* __restrict__ feats,
    __hip_bfloat16* __restrict__ featsT)
{
    __shared__ float tile[64][65];
    const int t = threadIdx.x;
    const int p0 = blockIdx.x * 64;
    const int c0 = blockIdx.y * 64;
#pragma unroll
    for (int i = 0; i < 4; ++i) {
        int c = (t >> 4) + i * 16;
        int p4 = (t & 15) * 4;
        float4 v = *(const float4*)(feats + (size_t)(c0 + c) * NPIX + p0 + p4);
        tile[c][p4 + 0] = v.x;
        tile[c][p4 + 1] = v.y;
        tile[c][p4 + 2] = v.z;
        tile[c][p4 + 3] = v.w;
    }
    __syncthreads();
#pragma unroll
    for (int i = 0; i < 2; ++i) {
        int p = (t >> 3) + i * 32;
        int cc = (t & 7) * 8;
        union { __hip_bfloat16 h[8]; uint4 u4; } pk;
#pragma unroll
        for (int j = 0; j < 8; ++j) pk.h[j] = __float2bfloat16(tile[cc + j][p]);
        *(uint4*)(featsT + (size_t)(p0 + p) * C_IN + c0 + cc) = pk.u4;
    }
}

// ---------------------------------------------------------------------------
// Kernel 2: line pool. 256 thr = 4 lines x 64 lanes; lane owns 2 channels
// (uint gathers). feat layout k' = p*128 + c (coalesced uint stores);
// w1 is permuted to the same k order.
// ---------------------------------------------------------------------------
__global__ __launch_bounds__(256) void pool_kernel(
    const __hip_bfloat16* __restrict__ loi,   // (NPIX, 128) bf16 channel-last
    const float* __restrict__ lines,          // (N_LINES, 4)
    __hip_bfloat16* __restrict__ feat)        // (N_LINES, 1024), k' = p*128+c
{
    __shared__ int   offs[4][N_PTS0][4];      // uint-index base (elements/2)
    __shared__ float wts[4][N_PTS0][4];
    const int g = threadIdx.x >> 6;   // line group in block
    const int t = threadIdx.x & 63;   // lane; owns channels 2t, 2t+1
    const int l = blockIdx.x * 4 + g;

    if (t < N_PTS0) {
        int j = t;
        float tt = (float)j * (1.0f / 31.0f);
        float U0 = lines[4 * l + 0], U1 = lines[4 * l + 1];
        float V0 = lines[4 * l + 2], V1 = lines[4 * l + 3];
        float px = U0 * tt + V0 * (1.0f - tt) - 0.5f;
        float py = U1 * tt + V1 * (1.0f - tt) - 0.5f;
        float px0 = fminf(fmaxf(floorf(px), 0.0f), 127.0f);
        float py0 = fminf(fmaxf(floorf(py), 0.0f), 127.0f);
        float px1 = fminf(fmaxf(px0 + 1.0f, 0.0f), 127.0f);
        float py1 = fminf(fmaxf(py0 + 1.0f, 0.0f), 127.0f);
        int ix0 = (int)px0, iy0 = (int)py0, ix1 = (int)px1, iy1 = (int)py1;
        float wx0 = px1 - px, wx1 = px - px0;
        float wy0 = py1 - py, wy1 = py - py0;
        offs[g][j][0] = (iy0 * HW + ix0) * 64;
        offs[g][j][1] = (iy1 * HW + ix0) * 64;
        offs[g][j][2] = (iy0 * HW + ix1) * 64;
        offs[g][j][3] = (iy1 * HW + ix1) * 64;
        wts[g][j][0] = wy0 * wx0;
        wts[g][j][1] = wy1 * wx0;
        wts[g][j][2] = wy0 * wx1;
        wts[g][j][3] = wy1 * wx1;
    }
    __syncthreads();

    const unsigned int* loi32 = (const unsigned int*)loi;
    unsigned int* featw = (unsigned int*)(feat + (size_t)l * (N_PTS1 * DIM_LOI));

#pragma unroll
    for (int p = 0; p < N_PTS1; ++p) {
        float b0 = -INFINITY, b1 = -INFINITY;
#pragma unroll
        for (int q = 0; q < 4; ++q) {
            int j = p * 4 + q;
            unsigned int v0 = loi32[offs[g][j][0] + t];
            unsigned int v1 = loi32[offs[g][j][1] + t];
            unsigned int v2 = loi32[offs[g][j][2] + t];
            unsigned int v3 = loi32[offs[g][j][3] + t];
            float w0 = wts[g][j][0], w1 = wts[g][j][1];
            float w2 = wts[g][j][2], w3 = wts[g][j][3];
            float sl = w0 * __uint_as_float(v0 << 16)
                     + w1 * __uint_as_float(v1 << 16)
                     + w2 * __uint_as_float(v2 << 16)
                     + w3 * __uint_as_float(v3 << 16);
            float sh = w0 * __uint_as_float(v0 & 0xffff0000u)
                     + w1 * __uint_as_float(v1 & 0xffff0000u)
                     + w2 * __uint_as_float(v2 & 0xffff0000u)
                     + w3 * __uint_as_float(v3 & 0xffff0000u);
            b0 = fmaxf(b0, sl);
            b1 = fmaxf(b1, sh);
        }
        union { __hip_bfloat16 h[2]; unsigned int u; } pk;
        pk.h[0] = __float2bfloat16(b0);
        pk.h[1] = __float2bfloat16(b1);
        featw[p * 64 + t] = pk.u;   // element p*128 + 2t
    }
}

// ---------------------------------------------------------------------------
// fp32 -> bf16 conversion, and permuting conversion (w1: k = c*8+p -> p*128+c)
// ---------------------------------------------------------------------------
__global__ __launch_bounds__(256) void to_bf16(
    const float* __restrict__ src, __hip_bfloat16* __restrict__ dst, int n4)
{
    int i = blockIdx.x * blockDim.x + threadIdx.x;
    if (i < n4) {
        float4 v = *(const float4*)(src + (size_t)i * 4);
        dst[(size_t)i * 4 + 0] = __float2bfloat16(v.x);
        dst[(size_t)i * 4 + 1] = __float2bfloat16(v.y);
        dst[(size_t)i * 4 + 2] = __float2bfloat16(v.z);
        dst[(size_t)i * 4 + 3] = __float2bfloat16(v.w);
    }
}

__global__ __launch_bounds__(256) void permute_w1(
    const float* __restrict__ w1, __hip_bfloat16* __restrict__ w1p)
{
    int n = blockIdx.x;                     // 0..1023
    const float* src = w1 + (size_t)n * 1024;
    __hip_bfloat16* dst = w1p + (size_t)n * 1024;
    for (int k = threadIdx.x; k < 1024; k += 256) {
        int p = k >> 7, c = k & 127;        // k' = p*128 + c
        dst[k] = __float2bfloat16(src[c * 8 + p]);
    }
}

// ---------------------------------------------------------------------------
// MFMA bf16 GEMM: out[m][n] = act(sum_k A[m][k]*B[n][k] + bias[n])
// 128x128 tile, BK=32, 4 waves in 2x2, each wave 4x4 of 16x16x32 MFMA.
// Grid: x = n-tiles, y = m-tiles, so A-sharing blocks are consecutive (L2).
// ---------------------------------------------------------------------------
template <int RELU, typename OutT>
__global__ __launch_bounds__(256) void mfma_gemm(
    const __hip_bfloat16* __restrict__ A,   // (M, K) row-major
    const __hip_bfloat16* __restrict__ B,   // (N, K) row-major (= B^T)
    const float* __restrict__ bias,         // (N)
    OutT* __restrict__ out,                 // (M, N)
    int M, int N, int K)
{
    __shared__ __hip_bfloat16 As[128 * 32];   // 8 KB
    __shared__ __hip_bfloat16 Bs[128 * 32];   // 8 KB
    const int tid  = threadIdx.x;
    const int lane = tid & 63;
    const int wave = tid >> 6;
    const int wr = wave >> 1, wc = wave & 1;    // 2x2 wave grid
    const int quad = lane >> 4;
    const int l16  = lane & 15;
    const int n0 = blockIdx.x * 128, m0 = blockIdx.y * 128;

    f32x4 acc[4][4];
#pragma unroll
    for (int i = 0; i < 4; ++i)
#pragma unroll
        for (int j = 0; j < 4; ++j) { f32x4 z = {0.f, 0.f, 0.f, 0.f}; acc[i][j] = z; }

    for (int k0 = 0; k0 < K; k0 += 32) {
        // ---- stage A,B tiles: 8 KB each; 2 sites x 256 thr x 16 B ----
#pragma unroll
        for (int s = 0; s < 2; ++s) {
            int li  = s * 256 + tid;         // 16B-chunk index 0..511
            int row = li >> 2;               // 0..127
            int ke  = (li & 3) * 8;          // element offset in k
            const __hip_bfloat16* ga = A + (size_t)(m0 + row) * K + k0 + ke;
            const __hip_bfloat16* gb = B + (size_t)(n0 + row) * K + k0 + ke;
            int chunk = s * 256 + (tid & ~63);  // wave-uniform base chunk
            __builtin_amdgcn_global_load_lds(
                (const __attribute__((address_space(1))) unsigned int*)ga,
                (__attribute__((address_space(3))) unsigned int*)(As + chunk * 8),
                16, 0, 0);
            __builtin_amdgcn_global_load_lds(
                (const __attribute__((address_space(1))) unsigned int*)gb,
                (__attribute__((address_space(3))) unsigned int*)(Bs + chunk * 8),
                16, 0, 0);
        }
        __syncthreads();

        // ---- fragments + MFMA ----
        short8 af[4], bf[4];
#pragma unroll
        for (int mt = 0; mt < 4; ++mt) {
            int row = wr * 64 + mt * 16 + l16;
            af[mt] = *(const short8*)((const short*)As + row * 32 + quad * 8);
        }
#pragma unroll
        for (int nt = 0; nt < 4; ++nt) {
            int row = wc * 64 + nt * 16 + l16;
            bf[nt] = *(const short8*)((const short*)Bs + row * 32 + quad * 8);
        }
#pragma unroll
        for (int mt = 0; mt < 4; ++mt)
#pragma unroll
            for (int nt = 0; nt < 4; ++nt)
                acc[mt][nt] = __builtin_amdgcn_mfma_f32_16x16x32_bf16(
                    af[mt], bf[nt], acc[mt][nt], 0, 0, 0);
        __syncthreads();
    }

    // ---- epilogue: C row = quad*4 + r, col = l16 ----
#pragma unroll
    for (int nt = 0; nt < 4; ++nt) {
        int n = n0 + wc * 64 + nt * 16 + l16;
        float bv = bias[n];
#pragma unroll
        for (int mt = 0; mt < 4; ++mt) {
            int mbase = m0 + wr * 64 + mt * 16 + quad * 4;
#pragma unroll
            for (int r = 0; r < 4; ++r) {
                float v = acc[mt][nt][r] + bv;
                if (RELU) v = v > 0.0f ? v : 0.0f;
                out[(size_t)(mbase + r) * N + n] = (OutT)v;
            }
        }
    }
}

// ---------------------------------------------------------------------------
// Head: one wave per line: logits[l][n] = sum_k x2[l][k]*w3[n][k] + b3[n]
// ---------------------------------------------------------------------------
__global__ __launch_bounds__(256) void head_kernel(
    const __hip_bfloat16* __restrict__ x2,  // (N_LINES, 1024) bf16
    const float* __restrict__ w3,           // (3, 1024)
    const float* __restrict__ b3,           // (3)
    float* __restrict__ out)                // (N_LINES, 3)
{
    const int gtid = blockIdx.x * blockDim.x + threadIdx.x;
    const int l = gtid >> 6;
    const int lane = threadIdx.x & 63;
    if (l >= N_LINES) return;
    const __hip_bfloat16* xr = x2 + (size_t)l * DIM_FC;
    float s0 = 0.0f, s1 = 0.0f, s2 = 0.0f;
#pragma unroll
    for (int it = 0; it < 4; ++it) {
        int k = it * 256 + lane * 4;
        ushort4 xv = *(const ushort4*)(xr + k);
        float x0 = __uint_as_float((unsigned)xv.x << 16);
        float x1 = __uint_as_float((unsigned)xv.y << 16);
        float x2v = __uint_as_float((unsigned)xv.z << 16);
        float x3 = __uint_as_float((unsigned)xv.w << 16);
        float4 wa = *(const float4*)(w3 + 0 * DIM_FC + k);
        float4 wb = *(const float4*)(w3 + 1 * DIM_FC + k);
        float4 wc = *(const float4*)(w3 + 2 * DIM_FC + k);
        s0 += x0 * wa.x + x1 * wa.y + x2v * wa.z + x3 * wa.w;
        s1 += x0 * wb.x + x1 * wb.y + x2v * wb.z + x3 * wb.w;
        s2 += x0 * wc.x + x1 * wc.y + x2v * wc.z + x3 * wc.w;
    }
#pragma unroll
    for (int off = 32; off > 0; off >>= 1) {
        s0 += __shfl_xor(s0, off);
        s1 += __shfl_xor(s1, off);
        s2 += __shfl_xor(s2, off);
    }
    if (lane == 0) {
        out[(size_t)l * 3 + 0] = s0 + b3[0];
        out[(size_t)l * 3 + 1] = s1 + b3[1];
        out[(size_t)l * 3 + 2] = s2 + b3[2];
    }
}

// ---------------------------------------------------------------------------
extern "C" void kernel_launch(void* const* d_in, const int* in_sizes, int n_in,
                              void* d_out, int out_size, void* d_ws, size_t ws_size,
                              hipStream_t stream) {
    const float* features = (const float*)d_in[0];  // (1,256,128,128)
    const float* lines    = (const float*)d_in[1];  // (16000,4)
    const float* w_fc1    = (const float*)d_in[2];  // (128,256)
    const float* b_fc1    = (const float*)d_in[3];  // (128)
    const float* w1       = (const float*)d_in[4];  // (1024,1024)
    const float* b1       = (const float*)d_in[5];  // (1024)
    const float* w2       = (const float*)d_in[6];  // (1024,1024)
    const float* b2       = (const float*)d_in[7];  // (1024)
    const float* w3       = (const float*)d_in[8];  // (3,1024)
    const float* b3       = (const float*)d_in[9];  // (3)
    float* out = (float*)d_out;

    // workspace layout (bytes):
    // loi    bf16 : 4 MB    @ 0
    // featb  bf16 : 32 MB   @ 8 MB   (x2b reuses this after GEMM1)
    // x1b    bf16 : 32 MB   @ 40 MB
    // w1b    bf16 : 2 MB    @ 72 MB
    // w2b    bf16 : 2 MB    @ 74 MB
    // featsT bf16 : 8 MB    @ 76 MB
    // wfc1b  bf16 : 64 KB   @ 84 MB
    char* ws = (char*)d_ws;
    __hip_bfloat16* loi    = (__hip_bfloat16*)ws;
    __hip_bfloat16* featb  = (__hip_bfloat16*)(ws + (size_t)8 * 1024 * 1024);
    __hip_bfloat16* x1b    = (__hip_bfloat16*)(ws + (size_t)40 * 1024 * 1024);
    __hip_bfloat16* x2b    = featb;   // reuse (featb dead after GEMM1)
    __hip_bfloat16* w1b    = (__hip_bfloat16*)(ws + (size_t)72 * 1024 * 1024);
    __hip_bfloat16* w2b    = (__hip_bfloat16*)(ws + (size_t)74 * 1024 * 1024);
    __hip_bfloat16* featsT = (__hip_bfloat16*)(ws + (size_t)76 * 1024 * 1024);
    __hip_bfloat16* wfc1b  = (__hip_bfloat16*)(ws + (size_t)84 * 1024 * 1024);

    // 0) precision conversions / permutations
    transpose_feats<<<dim3(NPIX / 64, C_IN / 64), 256, 0, stream>>>(features, featsT);
    to_bf16<<<dim3((DIM_LOI * C_IN / 4 + 255) / 256), 256, 0, stream>>>(w_fc1, wfc1b, DIM_LOI * C_IN / 4);
    permute_w1<<<dim3(DIM_FC), 256, 0, stream>>>(w1, w1b);
    to_bf16<<<dim3((DIM_FC * DIM_FC / 4 + 255) / 256), 256, 0, stream>>>(w2, w2b, DIM_FC * DIM_FC / 4);

    // 1) conv1x1 as MFMA GEMM: loi[p][o] = relu(featsT[p][:] . wfc1b[o][:] + b_fc1[o])
    mfma_gemm<1, __hip_bfloat16><<<dim3(DIM_LOI / 128, NPIX / 128), 256, 0, stream>>>(
        featsT, wfc1b, b_fc1, loi, NPIX, DIM_LOI, C_IN);

    // 2) line pooling -> featb (16000,1024) bf16, k' = p*128+c
    pool_kernel<<<dim3(N_LINES / 4), 256, 0, stream>>>(loi, lines, featb);

    // 3) x1 = relu(feat @ w1p^T + b1)
    mfma_gemm<1, __hip_bfloat16><<<dim3(DIM_FC / 128, N_LINES / 128), 256, 0, stream>>>(
        featb, w1b, b1, x1b, N_LINES, DIM_FC, DIM_FC);

    // 4) x2 = relu(x1 @ w2^T + b2)
    mfma_gemm<1, __hip_bfloat16><<<dim3(DIM_FC / 128, N_LINES / 128), 256, 0, stream>>>(
        x1b, w2b, b2, x2b, N_LINES, DIM_FC, DIM_FC);

    // 5) logits = x2 @ w3^T + b3
    head_kernel<<<dim3((N_LINES * 64 + 255) / 256), 256, 0, stream>>>(x2b, w3, b3, out);
}

// Round 5
// 244.206 us; speedup vs baseline: 4.1532x; 1.0444x over previous
//
#include <hip/hip_runtime.h>
#include <hip/hip_bf16.h>
#include <math.h>

// Problem dims (fixed)
#define C_IN 256
#define HW 128          // H = W = 128
#define NPIX (HW*HW)    // 16384
#define DIM_LOI 128
#define N_LINES 16000
#define N_PTS0 32
#define N_PTS1 8
#define DIM_FC 1024
#define N_LABELS 3

typedef __attribute__((ext_vector_type(8))) short short8;   // 8 bf16 = 4 VGPRs
typedef __attribute__((ext_vector_type(4))) float f32x4;

// ---------------------------------------------------------------------------
// Transpose + bf16: features (256, 16384) fp32 -> featsT (16384, 256) bf16
// ---------------------------------------------------------------------------
__global__ __launch_bounds__(256) void transpose_feats(
    const float* __restrict__ feats,
    __hip_bfloat16* __restrict__ featsT)
{
    __shared__ float tile[64][65];
    const int t = threadIdx.x;
    const int p0 = blockIdx.x * 64;
    const int c0 = blockIdx.y * 64;
#pragma unroll
    for (int i = 0; i < 4; ++i) {
        int c = (t >> 4) + i * 16;
        int p4 = (t & 15) * 4;
        float4 v = *(const float4*)(feats + (size_t)(c0 + c) * NPIX + p0 + p4);
        tile[c][p4 + 0] = v.x;
        tile[c][p4 + 1] = v.y;
        tile[c][p4 + 2] = v.z;
        tile[c][p4 + 3] = v.w;
    }
    __syncthreads();
#pragma unroll
    for (int i = 0; i < 2; ++i) {
        int p = (t >> 3) + i * 32;
        int cc = (t & 7) * 8;
        union { __hip_bfloat16 h[8]; uint4 u4; } pk;
#pragma unroll
        for (int j = 0; j < 8; ++j) pk.h[j] = __float2bfloat16(tile[cc + j][p]);
        *(uint4*)(featsT + (size_t)(p0 + p) * C_IN + c0 + cc) = pk.u4;
    }
}

// ---------------------------------------------------------------------------
// Kernel 2: line pool. 256 thr = 4 lines x 64 lanes; lane owns 2 channels
// (uint gathers). feat layout k' = p*128 + c (coalesced uint stores);
// w1 is permuted to the same k order.
// ---------------------------------------------------------------------------
__global__ __launch_bounds__(256) void pool_kernel(
    const __hip_bfloat16* __restrict__ loi,   // (NPIX, 128) bf16 channel-last
    const float* __restrict__ lines,          // (N_LINES, 4)
    __hip_bfloat16* __restrict__ feat)        // (N_LINES, 1024), k' = p*128+c
{
    __shared__ int   offs[4][N_PTS0][4];      // uint-index base (elements/2)
    __shared__ float wts[4][N_PTS0][4];
    const int g = threadIdx.x >> 6;   // line group in block
    const int t = threadIdx.x & 63;   // lane; owns channels 2t, 2t+1
    const int l = blockIdx.x * 4 + g;

    if (t < N_PTS0) {
        int j = t;
        float tt = (float)j * (1.0f / 31.0f);
        float U0 = lines[4 * l + 0], U1 = lines[4 * l + 1];
        float V0 = lines[4 * l + 2], V1 = lines[4 * l + 3];
        float px = U0 * tt + V0 * (1.0f - tt) - 0.5f;
        float py = U1 * tt + V1 * (1.0f - tt) - 0.5f;
        float px0 = fminf(fmaxf(floorf(px), 0.0f), 127.0f);
        float py0 = fminf(fmaxf(floorf(py), 0.0f), 127.0f);
        float px1 = fminf(fmaxf(px0 + 1.0f, 0.0f), 127.0f);
        float py1 = fminf(fmaxf(py0 + 1.0f, 0.0f), 127.0f);
        int ix0 = (int)px0, iy0 = (int)py0, ix1 = (int)px1, iy1 = (int)py1;
        float wx0 = px1 - px, wx1 = px - px0;
        float wy0 = py1 - py, wy1 = py - py0;
        offs[g][j][0] = (iy0 * HW + ix0) * 64;
        offs[g][j][1] = (iy1 * HW + ix0) * 64;
        offs[g][j][2] = (iy0 * HW + ix1) * 64;
        offs[g][j][3] = (iy1 * HW + ix1) * 64;
        wts[g][j][0] = wy0 * wx0;
        wts[g][j][1] = wy1 * wx0;
        wts[g][j][2] = wy0 * wx1;
        wts[g][j][3] = wy1 * wx1;
    }
    __syncthreads();

    const unsigned int* loi32 = (const unsigned int*)loi;
    unsigned int* featw = (unsigned int*)(feat + (size_t)l * (N_PTS1 * DIM_LOI));

#pragma unroll
    for (int p = 0; p < N_PTS1; ++p) {
        float b0 = -INFINITY, b1 = -INFINITY;
#pragma unroll
        for (int q = 0; q < 4; ++q) {
            int j = p * 4 + q;
            unsigned int v0 = loi32[offs[g][j][0] + t];
            unsigned int v1 = loi32[offs[g][j][1] + t];
            unsigned int v2 = loi32[offs[g][j][2] + t];
            unsigned int v3 = loi32[offs[g][j][3] + t];
            float w0 = wts[g][j][0], w1 = wts[g][j][1];
            float w2 = wts[g][j][2], w3 = wts[g][j][3];
            float sl = w0 * __uint_as_float(v0 << 16)
                     + w1 * __uint_as_float(v1 << 16)
                     + w2 * __uint_as_float(v2 << 16)
                     + w3 * __uint_as_float(v3 << 16);
            float sh = w0 * __uint_as_float(v0 & 0xffff0000u)
                     + w1 * __uint_as_float(v1 & 0xffff0000u)
                     + w2 * __uint_as_float(v2 & 0xffff0000u)
                     + w3 * __uint_as_float(v3 & 0xffff0000u);
            b0 = fmaxf(b0, sl);
            b1 = fmaxf(b1, sh);
        }
        union { __hip_bfloat16 h[2]; unsigned int u; } pk;
        pk.h[0] = __float2bfloat16(b0);
        pk.h[1] = __float2bfloat16(b1);
        featw[p * 64 + t] = pk.u;   // element p*128 + 2t
    }
}

// ---------------------------------------------------------------------------
// fp32 -> bf16 conversion, and permuting conversion (w1: k = c*8+p -> p*128+c)
// ---------------------------------------------------------------------------
__global__ __launch_bounds__(256) void to_bf16(
    const float* __restrict__ src, __hip_bfloat16* __restrict__ dst, int n4)
{
    int i = blockIdx.x * blockDim.x + threadIdx.x;
    if (i < n4) {
        float4 v = *(const float4*)(src + (size_t)i * 4);
        dst[(size_t)i * 4 + 0] = __float2bfloat16(v.x);
        dst[(size_t)i * 4 + 1] = __float2bfloat16(v.y);
        dst[(size_t)i * 4 + 2] = __float2bfloat16(v.z);
        dst[(size_t)i * 4 + 3] = __float2bfloat16(v.w);
    }
}

__global__ __launch_bounds__(256) void permute_w1(
    const float* __restrict__ w1, __hip_bfloat16* __restrict__ w1p)
{
    int n = blockIdx.x;                     // 0..1023
    const float* src = w1 + (size_t)n * 1024;
    __hip_bfloat16* dst = w1p + (size_t)n * 1024;
    for (int k = threadIdx.x; k < 1024; k += 256) {
        int p = k >> 7, c = k & 127;        // k' = p*128 + c
        dst[k] = __float2bfloat16(src[c * 8 + p]);
    }
}

// ---------------------------------------------------------------------------
// MFMA bf16 GEMM: out[m][n] = act(sum_k A[m][k]*B[n][k] + bias[n])
// 128x128 tile, BK=32, 4 waves in 2x2, each wave 4x4 of 16x16x32 MFMA.
// 1D grid + XCD-aware swizzle: lid%8 = XCD (round-robin dispatch), so blocks
// on the SAME XCD get consecutive g = xcd*per + lid/8; with n fastest in g,
// 8 same-XCD-consecutive blocks share one A-tile -> A hits that XCD's L2.
// ---------------------------------------------------------------------------
template <int RELU, typename OutT>
__global__ __launch_bounds__(256) void mfma_gemm(
    const __hip_bfloat16* __restrict__ A,   // (M, K) row-major
    const __hip_bfloat16* __restrict__ B,   // (N, K) row-major (= B^T)
    const float* __restrict__ bias,         // (N)
    OutT* __restrict__ out,                 // (M, N)
    int M, int N, int K, int n_tiles)
{
    __shared__ __hip_bfloat16 As[128 * 32];   // 8 KB
    __shared__ __hip_bfloat16 Bs[128 * 32];   // 8 KB
    const int tid  = threadIdx.x;
    const int lane = tid & 63;
    const int wave = tid >> 6;
    const int wr = wave >> 1, wc = wave & 1;    // 2x2 wave grid
    const int quad = lane >> 4;
    const int l16  = lane & 15;

    // XCD-aware relabel (grid must be divisible by 8)
    const int lid = blockIdx.x;
    const int per = gridDim.x >> 3;
    const int g   = (lid & 7) * per + (lid >> 3);
    const int n0 = (g % n_tiles) * 128;
    const int m0 = (g / n_tiles) * 128;

    f32x4 acc[4][4];
#pragma unroll
    for (int i = 0; i < 4; ++i)
#pragma unroll
        for (int j = 0; j < 4; ++j) { f32x4 z = {0.f, 0.f, 0.f, 0.f}; acc[i][j] = z; }

    for (int k0 = 0; k0 < K; k0 += 32) {
        // ---- stage A,B tiles: 8 KB each; 2 sites x 256 thr x 16 B ----
#pragma unroll
        for (int s = 0; s < 2; ++s) {
            int li  = s * 256 + tid;         // 16B-chunk index 0..511
            int row = li >> 2;               // 0..127
            int ke  = (li & 3) * 8;          // element offset in k
            const __hip_bfloat16* ga = A + (size_t)(m0 + row) * K + k0 + ke;
            const __hip_bfloat16* gb = B + (size_t)(n0 + row) * K + k0 + ke;
            int chunk = s * 256 + (tid & ~63);  // wave-uniform base chunk
            __builtin_amdgcn_global_load_lds(
                (const __attribute__((address_space(1))) unsigned int*)ga,
                (__attribute__((address_space(3))) unsigned int*)(As + chunk * 8),
                16, 0, 0);
            __builtin_amdgcn_global_load_lds(
                (const __attribute__((address_space(1))) unsigned int*)gb,
                (__attribute__((address_space(3))) unsigned int*)(Bs + chunk * 8),
                16, 0, 0);
        }
        __syncthreads();

        // ---- fragments + MFMA ----
        short8 af[4], bf[4];
#pragma unroll
        for (int mt = 0; mt < 4; ++mt) {
            int row = wr * 64 + mt * 16 + l16;
            af[mt] = *(const short8*)((const short*)As + row * 32 + quad * 8);
        }
#pragma unroll
        for (int nt = 0; nt < 4; ++nt) {
            int row = wc * 64 + nt * 16 + l16;
            bf[nt] = *(const short8*)((const short*)Bs + row * 32 + quad * 8);
        }
#pragma unroll
        for (int mt = 0; mt < 4; ++mt)
#pragma unroll
            for (int nt = 0; nt < 4; ++nt)
                acc[mt][nt] = __builtin_amdgcn_mfma_f32_16x16x32_bf16(
                    af[mt], bf[nt], acc[mt][nt], 0, 0, 0);
        __syncthreads();
    }

    // ---- epilogue: C row = quad*4 + r, col = l16 ----
#pragma unroll
    for (int nt = 0; nt < 4; ++nt) {
        int n = n0 + wc * 64 + nt * 16 + l16;
        float bv = bias[n];
#pragma unroll
        for (int mt = 0; mt < 4; ++mt) {
            int mbase = m0 + wr * 64 + mt * 16 + quad * 4;
#pragma unroll
            for (int r = 0; r < 4; ++r) {
                float v = acc[mt][nt][r] + bv;
                if (RELU) v = v > 0.0f ? v : 0.0f;
                out[(size_t)(mbase + r) * N + n] = (OutT)v;
            }
        }
    }
}

// ---------------------------------------------------------------------------
// Head: one wave per line: logits[l][n] = sum_k x2[l][k]*w3[n][k] + b3[n]
// ---------------------------------------------------------------------------
__global__ __launch_bounds__(256) void head_kernel(
    const __hip_bfloat16* __restrict__ x2,  // (N_LINES, 1024) bf16
    const float* __restrict__ w3,           // (3, 1024)
    const float* __restrict__ b3,           // (3)
    float* __restrict__ out)                // (N_LINES, 3)
{
    const int gtid = blockIdx.x * blockDim.x + threadIdx.x;
    const int l = gtid >> 6;
    const int lane = threadIdx.x & 63;
    if (l >= N_LINES) return;
    const __hip_bfloat16* xr = x2 + (size_t)l * DIM_FC;
    float s0 = 0.0f, s1 = 0.0f, s2 = 0.0f;
#pragma unroll
    for (int it = 0; it < 4; ++it) {
        int k = it * 256 + lane * 4;
        ushort4 xv = *(const ushort4*)(xr + k);
        float x0 = __uint_as_float((unsigned)xv.x << 16);
        float x1 = __uint_as_float((unsigned)xv.y << 16);
        float x2v = __uint_as_float((unsigned)xv.z << 16);
        float x3 = __uint_as_float((unsigned)xv.w << 16);
        float4 wa = *(const float4*)(w3 + 0 * DIM_FC + k);
        float4 wb = *(const float4*)(w3 + 1 * DIM_FC + k);
        float4 wc = *(const float4*)(w3 + 2 * DIM_FC + k);
        s0 += x0 * wa.x + x1 * wa.y + x2v * wa.z + x3 * wa.w;
        s1 += x0 * wb.x + x1 * wb.y + x2v * wb.z + x3 * wb.w;
        s2 += x0 * wc.x + x1 * wc.y + x2v * wc.z + x3 * wc.w;
    }
#pragma unroll
    for (int off = 32; off > 0; off >>= 1) {
        s0 += __shfl_xor(s0, off);
        s1 += __shfl_xor(s1, off);
        s2 += __shfl_xor(s2, off);
    }
    if (lane == 0) {
        out[(size_t)l * 3 + 0] = s0 + b3[0];
        out[(size_t)l * 3 + 1] = s1 + b3[1];
        out[(size_t)l * 3 + 2] = s2 + b3[2];
    }
}

// ---------------------------------------------------------------------------
extern "C" void kernel_launch(void* const* d_in, const int* in_sizes, int n_in,
                              void* d_out, int out_size, void* d_ws, size_t ws_size,
                              hipStream_t stream) {
    const float* features = (const float*)d_in[0];  // (1,256,128,128)
    const float* lines    = (const float*)d_in[1];  // (16000,4)
    const float* w_fc1    = (const float*)d_in[2];  // (128,256)
    const float* b_fc1    = (const float*)d_in[3];  // (128)
    const float* w1       = (const float*)d_in[4];  // (1024,1024)
    const float* b1       = (const float*)d_in[5];  // (1024)
    const float* w2       = (const float*)d_in[6];  // (1024,1024)
    const float* b2       = (const float*)d_in[7];  // (1024)
    const float* w3       = (const float*)d_in[8];  // (3,1024)
    const float* b3       = (const float*)d_in[9];  // (3)
    float* out = (float*)d_out;

    // workspace layout (bytes):
    // loi    bf16 : 4 MB    @ 0
    // featb  bf16 : 32 MB   @ 8 MB   (x2b reuses this after GEMM1)
    // x1b    bf16 : 32 MB   @ 40 MB
    // w1b    bf16 : 2 MB    @ 72 MB
    // w2b    bf16 : 2 MB    @ 74 MB
    // featsT bf16 : 8 MB    @ 76 MB
    // wfc1b  bf16 : 64 KB   @ 84 MB
    char* ws = (char*)d_ws;
    __hip_bfloat16* loi    = (__hip_bfloat16*)ws;
    __hip_bfloat16* featb  = (__hip_bfloat16*)(ws + (size_t)8 * 1024 * 1024);
    __hip_bfloat16* x1b    = (__hip_bfloat16*)(ws + (size_t)40 * 1024 * 1024);
    __hip_bfloat16* x2b    = featb;   // reuse (featb dead after GEMM1)
    __hip_bfloat16* w1b    = (__hip_bfloat16*)(ws + (size_t)72 * 1024 * 1024);
    __hip_bfloat16* w2b    = (__hip_bfloat16*)(ws + (size_t)74 * 1024 * 1024);
    __hip_bfloat16* featsT = (__hip_bfloat16*)(ws + (size_t)76 * 1024 * 1024);
    __hip_bfloat16* wfc1b  = (__hip_bfloat16*)(ws + (size_t)84 * 1024 * 1024);

    // 0) precision conversions / permutations
    transpose_feats<<<dim3(NPIX / 64, C_IN / 64), 256, 0, stream>>>(features, featsT);
    to_bf16<<<dim3((DIM_LOI * C_IN / 4 + 255) / 256), 256, 0, stream>>>(w_fc1, wfc1b, DIM_LOI * C_IN / 4);
    permute_w1<<<dim3(DIM_FC), 256, 0, stream>>>(w1, w1b);
    to_bf16<<<dim3((DIM_FC * DIM_FC / 4 + 255) / 256), 256, 0, stream>>>(w2, w2b, DIM_FC * DIM_FC / 4);

    // 1) conv1x1 as MFMA GEMM (grid 128, 1 n-tile)
    mfma_gemm<1, __hip_bfloat16><<<dim3(NPIX / 128), 256, 0, stream>>>(
        featsT, wfc1b, b_fc1, loi, NPIX, DIM_LOI, C_IN, 1);

    // 2) line pooling -> featb (16000,1024) bf16, k' = p*128+c
    pool_kernel<<<dim3(N_LINES / 4), 256, 0, stream>>>(loi, lines, featb);

    // 3) x1 = relu(feat @ w1p^T + b1)   grid 1000 = 125 m x 8 n
    mfma_gemm<1, __hip_bfloat16><<<dim3((N_LINES / 128) * (DIM_FC / 128)), 256, 0, stream>>>(
        featb, w1b, b1, x1b, N_LINES, DIM_FC, DIM_FC, DIM_FC / 128);

    // 4) x2 = relu(x1 @ w2^T + b2)
    mfma_gemm<1, __hip_bfloat16><<<dim3((N_LINES / 128) * (DIM_FC / 128)), 256, 0, stream>>>(
        x1b, w2b, b2, x2b, N_LINES, DIM_FC, DIM_FC, DIM_FC / 128);

    // 5) logits = x2 @ w3^T + b3
    head_kernel<<<dim3((N_LINES * 64 + 255) / 256), 256, 0, stream>>>(x2b, w3, b3, out);
}

// Round 6
// 226.374 us; speedup vs baseline: 4.4804x; 1.0788x over previous
//
#include <hip/hip_runtime.h>
#include <hip/hip_bf16.h>
#include <math.h>

// Problem dims (fixed)
#define C_IN 256
#define HW 128          // H = W = 128
#define NPIX (HW*HW)    // 16384
#define DIM_LOI 128
#define N_LINES 16000
#define N_PTS0 32
#define N_PTS1 8
#define DIM_FC 1024
#define N_LABELS 3

typedef __attribute__((ext_vector_type(8))) short short8;   // 8 bf16 = 4 VGPRs
typedef __attribute__((ext_vector_type(4))) float f32x4;

// ---------------------------------------------------------------------------
// Transpose + bf16: features (256, 16384) fp32 -> featsT (16384, 256) bf16
// ---------------------------------------------------------------------------
__global__ __launch_bounds__(256) void transpose_feats(
    const float* __restrict__ feats,
    __hip_bfloat16* __restrict__ featsT)
{
    __shared__ float tile[64][65];
    const int t = threadIdx.x;
    const int p0 = blockIdx.x * 64;
    const int c0 = blockIdx.y * 64;
#pragma unroll
    for (int i = 0; i < 4; ++i) {
        int c = (t >> 4) + i * 16;
        int p4 = (t & 15) * 4;
        float4 v = *(const float4*)(feats + (size_t)(c0 + c) * NPIX + p0 + p4);
        tile[c][p4 + 0] = v.x;
        tile[c][p4 + 1] = v.y;
        tile[c][p4 + 2] = v.z;
        tile[c][p4 + 3] = v.w;
    }
    __syncthreads();
#pragma unroll
    for (int i = 0; i < 2; ++i) {
        int p = (t >> 3) + i * 32;
        int cc = (t & 7) * 8;
        union { __hip_bfloat16 h[8]; uint4 u4; } pk;
#pragma unroll
        for (int j = 0; j < 8; ++j) pk.h[j] = __float2bfloat16(tile[cc + j][p]);
        *(uint4*)(featsT + (size_t)(p0 + p) * C_IN + c0 + cc) = pk.u4;
    }
}

// ---------------------------------------------------------------------------
// Kernel 2: line pool. 256 thr = 4 lines x 64 lanes; lane owns 2 channels
// (uint gathers). feat layout k' = p*128 + c (coalesced uint stores);
// w1 is permuted to the same k order.
// ---------------------------------------------------------------------------
__global__ __launch_bounds__(256) void pool_kernel(
    const __hip_bfloat16* __restrict__ loi,   // (NPIX, 128) bf16 channel-last
    const float* __restrict__ lines,          // (N_LINES, 4)
    __hip_bfloat16* __restrict__ feat)        // (N_LINES, 1024), k' = p*128+c
{
    __shared__ int   offs[4][N_PTS0][4];      // uint-index base (elements/2)
    __shared__ float wts[4][N_PTS0][4];
    const int g = threadIdx.x >> 6;   // line group in block
    const int t = threadIdx.x & 63;   // lane; owns channels 2t, 2t+1
    const int l = blockIdx.x * 4 + g;

    if (t < N_PTS0) {
        int j = t;
        float tt = (float)j * (1.0f / 31.0f);
        float U0 = lines[4 * l + 0], U1 = lines[4 * l + 1];
        float V0 = lines[4 * l + 2], V1 = lines[4 * l + 3];
        float px = U0 * tt + V0 * (1.0f - tt) - 0.5f;
        float py = U1 * tt + V1 * (1.0f - tt) - 0.5f;
        float px0 = fminf(fmaxf(floorf(px), 0.0f), 127.0f);
        float py0 = fminf(fmaxf(floorf(py), 0.0f), 127.0f);
        float px1 = fminf(fmaxf(px0 + 1.0f, 0.0f), 127.0f);
        float py1 = fminf(fmaxf(py0 + 1.0f, 0.0f), 127.0f);
        int ix0 = (int)px0, iy0 = (int)py0, ix1 = (int)px1, iy1 = (int)py1;
        float wx0 = px1 - px, wx1 = px - px0;
        float wy0 = py1 - py, wy1 = py - py0;
        offs[g][j][0] = (iy0 * HW + ix0) * 64;
        offs[g][j][1] = (iy1 * HW + ix0) * 64;
        offs[g][j][2] = (iy0 * HW + ix1) * 64;
        offs[g][j][3] = (iy1 * HW + ix1) * 64;
        wts[g][j][0] = wy0 * wx0;
        wts[g][j][1] = wy1 * wx0;
        wts[g][j][2] = wy0 * wx1;
        wts[g][j][3] = wy1 * wx1;
    }
    __syncthreads();

    const unsigned int* loi32 = (const unsigned int*)loi;
    unsigned int* featw = (unsigned int*)(feat + (size_t)l * (N_PTS1 * DIM_LOI));

#pragma unroll
    for (int p = 0; p < N_PTS1; ++p) {
        float b0 = -INFINITY, b1 = -INFINITY;
#pragma unroll
        for (int q = 0; q < 4; ++q) {
            int j = p * 4 + q;
            unsigned int v0 = loi32[offs[g][j][0] + t];
            unsigned int v1 = loi32[offs[g][j][1] + t];
            unsigned int v2 = loi32[offs[g][j][2] + t];
            unsigned int v3 = loi32[offs[g][j][3] + t];
            float w0 = wts[g][j][0], w1 = wts[g][j][1];
            float w2 = wts[g][j][2], w3 = wts[g][j][3];
            float sl = w0 * __uint_as_float(v0 << 16)
                     + w1 * __uint_as_float(v1 << 16)
                     + w2 * __uint_as_float(v2 << 16)
                     + w3 * __uint_as_float(v3 << 16);
            float sh = w0 * __uint_as_float(v0 & 0xffff0000u)
                     + w1 * __uint_as_float(v1 & 0xffff0000u)
                     + w2 * __uint_as_float(v2 & 0xffff0000u)
                     + w3 * __uint_as_float(v3 & 0xffff0000u);
            b0 = fmaxf(b0, sl);
            b1 = fmaxf(b1, sh);
        }
        union { __hip_bfloat16 h[2]; unsigned int u; } pk;
        pk.h[0] = __float2bfloat16(b0);
        pk.h[1] = __float2bfloat16(b1);
        featw[p * 64 + t] = pk.u;   // element p*128 + 2t
    }
}

// ---------------------------------------------------------------------------
// fp32 -> bf16 conversion
// ---------------------------------------------------------------------------
__global__ __launch_bounds__(256) void to_bf16(
    const float* __restrict__ src, __hip_bfloat16* __restrict__ dst, int n4)
{
    int i = blockIdx.x * blockDim.x + threadIdx.x;
    if (i < n4) {
        float4 v = *(const float4*)(src + (size_t)i * 4);
        dst[(size_t)i * 4 + 0] = __float2bfloat16(v.x);
        dst[(size_t)i * 4 + 1] = __float2bfloat16(v.y);
        dst[(size_t)i * 4 + 2] = __float2bfloat16(v.z);
        dst[(size_t)i * 4 + 3] = __float2bfloat16(v.w);
    }
}

// ---------------------------------------------------------------------------
// permute_w1: k = c*8+p -> k' = p*128+c, coalesced reads via LDS staging.
// One block per output row n.
// ---------------------------------------------------------------------------
__global__ __launch_bounds__(256) void permute_w1(
    const float* __restrict__ w1, __hip_bfloat16* __restrict__ w1p)
{
    __shared__ float row[1024];
    const int n = blockIdx.x;
    const int t = threadIdx.x;
    // coalesced read: 256 thr x float4 = 4 KB
    ((float4*)row)[t] = ((const float4*)(w1 + (size_t)n * 1024))[t];
    __syncthreads();
    unsigned int* dst = (unsigned int*)(w1p + (size_t)n * 1024);
#pragma unroll
    for (int pass = 0; pass < 2; ++pass) {
        int j = pass * 256 + t;        // uint index; elements 2j, 2j+1
        int k0 = 2 * j, k1 = 2 * j + 1;
        float v0 = row[(k0 & 127) * 8 + (k0 >> 7)];
        float v1 = row[(k1 & 127) * 8 + (k1 >> 7)];
        union { __hip_bfloat16 h[2]; unsigned int u; } pk;
        pk.h[0] = __float2bfloat16(v0);
        pk.h[1] = __float2bfloat16(v1);
        dst[j] = pk.u;
    }
}

// ---------------------------------------------------------------------------
// MFMA bf16 GEMM, BK=64: out[m][n] = act(sum_k A[m][k]*B[n][k] + bias[n])
// 128x128 tile, 4 waves in 2x2, each wave 4x4 of 16x16x32 MFMA, 2 k-halves
// per iteration (half the barriers of BK=32).
// LDS: two 32-k panels per matrix, each in m97's [row][32] layout (64 B row
// stride -> no pathological bank conflicts; global_load_lds lane-contiguous
// by chunk construction: li -> panel=li>>9, row=(li&511)>>2, ke=(li&3)*8).
// XCD-aware swizzle: lid%8 = XCD, n fastest -> A-tile reused within one XCD.
// ---------------------------------------------------------------------------
template <int RELU, typename OutT>
__global__ __launch_bounds__(256) void mfma_gemm(
    const __hip_bfloat16* __restrict__ A,   // (M, K) row-major
    const __hip_bfloat16* __restrict__ B,   // (N, K) row-major (= B^T)
    const float* __restrict__ bias,         // (N)
    OutT* __restrict__ out,                 // (M, N)
    int M, int N, int K, int n_tiles)
{
    __shared__ __hip_bfloat16 As[128 * 64];   // 16 KB: panel0 [128][32], panel1 [128][32]
    __shared__ __hip_bfloat16 Bs[128 * 64];   // 16 KB
    const int tid  = threadIdx.x;
    const int lane = tid & 63;
    const int wave = tid >> 6;
    const int wr = wave >> 1, wc = wave & 1;    // 2x2 wave grid
    const int quad = lane >> 4;
    const int l16  = lane & 15;

    // XCD-aware relabel (grid must be divisible by 8)
    const int lid = blockIdx.x;
    const int per = gridDim.x >> 3;
    const int g   = (lid & 7) * per + (lid >> 3);
    const int n0 = (g % n_tiles) * 128;
    const int m0 = (g / n_tiles) * 128;

    f32x4 acc[4][4];
#pragma unroll
    for (int i = 0; i < 4; ++i)
#pragma unroll
        for (int j = 0; j < 4; ++j) { f32x4 z = {0.f, 0.f, 0.f, 0.f}; acc[i][j] = z; }

    for (int k0 = 0; k0 < K; k0 += 64) {
        // ---- stage A,B 128x64 tiles: 4 sites x 256 thr x 16 B each ----
#pragma unroll
        for (int s = 0; s < 4; ++s) {
            int li   = s * 256 + tid;          // chunk 0..1023
            int row  = (li & 511) >> 2;        // 0..127
            int ke   = (li >> 9) * 32 + (li & 3) * 8;  // k element offset 0..63
            const __hip_bfloat16* ga = A + (size_t)(m0 + row) * K + k0 + ke;
            const __hip_bfloat16* gb = B + (size_t)(n0 + row) * K + k0 + ke;
            int chunk = s * 256 + (tid & ~63); // wave-uniform base chunk
            __builtin_amdgcn_global_load_lds(
                (const __attribute__((address_space(1))) unsigned int*)ga,
                (__attribute__((address_space(3))) unsigned int*)(As + chunk * 8),
                16, 0, 0);
            __builtin_amdgcn_global_load_lds(
                (const __attribute__((address_space(1))) unsigned int*)gb,
                (__attribute__((address_space(3))) unsigned int*)(Bs + chunk * 8),
                16, 0, 0);
        }
        __syncthreads();

        // ---- two 32-k halves: fragments + MFMA ----
#pragma unroll
        for (int kh = 0; kh < 2; ++kh) {
            const short* ap = (const short*)As + kh * 4096;
            const short* bp = (const short*)Bs + kh * 4096;
            short8 af[4], bf[4];
#pragma unroll
            for (int mt = 0; mt < 4; ++mt) {
                int row = wr * 64 + mt * 16 + l16;
                af[mt] = *(const short8*)(ap + row * 32 + quad * 8);
            }
#pragma unroll
            for (int nt = 0; nt < 4; ++nt) {
                int row = wc * 64 + nt * 16 + l16;
                bf[nt] = *(const short8*)(bp + row * 32 + quad * 8);
            }
#pragma unroll
            for (int mt = 0; mt < 4; ++mt)
#pragma unroll
                for (int nt = 0; nt < 4; ++nt)
                    acc[mt][nt] = __builtin_amdgcn_mfma_f32_16x16x32_bf16(
                        af[mt], bf[nt], acc[mt][nt], 0, 0, 0);
        }
        __syncthreads();
    }

    // ---- epilogue: C row = quad*4 + r, col = l16 ----
#pragma unroll
    for (int nt = 0; nt < 4; ++nt) {
        int n = n0 + wc * 64 + nt * 16 + l16;
        float bv = bias[n];
#pragma unroll
        for (int mt = 0; mt < 4; ++mt) {
            int mbase = m0 + wr * 64 + mt * 16 + quad * 4;
#pragma unroll
            for (int r = 0; r < 4; ++r) {
                float v = acc[mt][nt][r] + bv;
                if (RELU) v = v > 0.0f ? v : 0.0f;
                out[(size_t)(mbase + r) * N + n] = (OutT)v;
            }
        }
    }
}

// ---------------------------------------------------------------------------
// Head: one wave per line: logits[l][n] = sum_k x2[l][k]*w3[n][k] + b3[n]
// ---------------------------------------------------------------------------
__global__ __launch_bounds__(256) void head_kernel(
    const __hip_bfloat16* __restrict__ x2,  // (N_LINES, 1024) bf16
    const float* __restrict__ w3,           // (3, 1024)
    const float* __restrict__ b3,           // (3)
    float* __restrict__ out)                // (N_LINES, 3)
{
    const int gtid = blockIdx.x * blockDim.x + threadIdx.x;
    const int l = gtid >> 6;
    const int lane = threadIdx.x & 63;
    if (l >= N_LINES) return;
    const __hip_bfloat16* xr = x2 + (size_t)l * DIM_FC;
    float s0 = 0.0f, s1 = 0.0f, s2 = 0.0f;
#pragma unroll
    for (int it = 0; it < 4; ++it) {
        int k = it * 256 + lane * 4;
        ushort4 xv = *(const ushort4*)(xr + k);
        float x0 = __uint_as_float((unsigned)xv.x << 16);
        float x1 = __uint_as_float((unsigned)xv.y << 16);
        float x2v = __uint_as_float((unsigned)xv.z << 16);
        float x3 = __uint_as_float((unsigned)xv.w << 16);
        float4 wa = *(const float4*)(w3 + 0 * DIM_FC + k);
        float4 wb = *(const float4*)(w3 + 1 * DIM_FC + k);
        float4 wc = *(const float4*)(w3 + 2 * DIM_FC + k);
        s0 += x0 * wa.x + x1 * wa.y + x2v * wa.z + x3 * wa.w;
        s1 += x0 * wb.x + x1 * wb.y + x2v * wb.z + x3 * wb.w;
        s2 += x0 * wc.x + x1 * wc.y + x2v * wc.z + x3 * wc.w;
    }
#pragma unroll
    for (int off = 32; off > 0; off >>= 1) {
        s0 += __shfl_xor(s0, off);
        s1 += __shfl_xor(s1, off);
        s2 += __shfl_xor(s2, off);
    }
    if (lane == 0) {
        out[(size_t)l * 3 + 0] = s0 + b3[0];
        out[(size_t)l * 3 + 1] = s1 + b3[1];
        out[(size_t)l * 3 + 2] = s2 + b3[2];
    }
}

// ---------------------------------------------------------------------------
extern "C" void kernel_launch(void* const* d_in, const int* in_sizes, int n_in,
                              void* d_out, int out_size, void* d_ws, size_t ws_size,
                              hipStream_t stream) {
    const float* features = (const float*)d_in[0];  // (1,256,128,128)
    const float* lines    = (const float*)d_in[1];  // (16000,4)
    const float* w_fc1    = (const float*)d_in[2];  // (128,256)
    const float* b_fc1    = (const float*)d_in[3];  // (128)
    const float* w1       = (const float*)d_in[4];  // (1024,1024)
    const float* b1       = (const float*)d_in[5];  // (1024)
    const float* w2       = (const float*)d_in[6];  // (1024,1024)
    const float* b2       = (const float*)d_in[7];  // (1024)
    const float* w3       = (const float*)d_in[8];  // (3,1024)
    const float* b3       = (const float*)d_in[9];  // (3)
    float* out = (float*)d_out;

    // workspace layout (bytes):
    // loi    bf16 : 4 MB    @ 0
    // featb  bf16 : 32 MB   @ 8 MB   (x2b reuses this after GEMM1)
    // x1b    bf16 : 32 MB   @ 40 MB
    // w1b    bf16 : 2 MB    @ 72 MB
    // w2b    bf16 : 2 MB    @ 74 MB
    // featsT bf16 : 8 MB    @ 76 MB
    // wfc1b  bf16 : 64 KB   @ 84 MB
    char* ws = (char*)d_ws;
    __hip_bfloat16* loi    = (__hip_bfloat16*)ws;
    __hip_bfloat16* featb  = (__hip_bfloat16*)(ws + (size_t)8 * 1024 * 1024);
    __hip_bfloat16* x1b    = (__hip_bfloat16*)(ws + (size_t)40 * 1024 * 1024);
    __hip_bfloat16* x2b    = featb;   // reuse (featb dead after GEMM1)
    __hip_bfloat16* w1b    = (__hip_bfloat16*)(ws + (size_t)72 * 1024 * 1024);
    __hip_bfloat16* w2b    = (__hip_bfloat16*)(ws + (size_t)74 * 1024 * 1024);
    __hip_bfloat16* featsT = (__hip_bfloat16*)(ws + (size_t)76 * 1024 * 1024);
    __hip_bfloat16* wfc1b  = (__hip_bfloat16*)(ws + (size_t)84 * 1024 * 1024);

    // 0) precision conversions / permutations
    transpose_feats<<<dim3(NPIX / 64, C_IN / 64), 256, 0, stream>>>(features, featsT);
    to_bf16<<<dim3((DIM_LOI * C_IN / 4 + 255) / 256), 256, 0, stream>>>(w_fc1, wfc1b, DIM_LOI * C_IN / 4);
    permute_w1<<<dim3(DIM_FC), 256, 0, stream>>>(w1, w1b);
    to_bf16<<<dim3((DIM_FC * DIM_FC / 4 + 255) / 256), 256, 0, stream>>>(w2, w2b, DIM_FC * DIM_FC / 4);

    // 1) conv1x1 as MFMA GEMM (grid 128, 1 n-tile, K=256 -> 4 iters)
    mfma_gemm<1, __hip_bfloat16><<<dim3(NPIX / 128), 256, 0, stream>>>(
        featsT, wfc1b, b_fc1, loi, NPIX, DIM_LOI, C_IN, 1);

    // 2) line pooling -> featb (16000,1024) bf16, k' = p*128+c
    pool_kernel<<<dim3(N_LINES / 4), 256, 0, stream>>>(loi, lines, featb);

    // 3) x1 = relu(feat @ w1p^T + b1)   grid 1000 = 125 m x 8 n
    mfma_gemm<1, __hip_bfloat16><<<dim3((N_LINES / 128) * (DIM_FC / 128)), 256, 0, stream>>>(
        featb, w1b, b1, x1b, N_LINES, DIM_FC, DIM_FC, DIM_FC / 128);

    // 4) x2 = relu(x1 @ w2^T + b2)
    mfma_gemm<1, __hip_bfloat16><<<dim3((N_LINES / 128) * (DIM_FC / 128)), 256, 0, stream>>>(
        x1b, w2b, b2, x2b, N_LINES, DIM_FC, DIM_FC, DIM_FC / 128);

    // 5) logits = x2 @ w3^T + b3
    head_kernel<<<dim3((N_LINES * 64 + 255) / 256), 256, 0, stream>>>(x2b, w3, b3, out);
}